// Round 2
// baseline (3555.150 us; speedup 1.0000x reference)
//
#include <hip/hip_runtime.h>
#include <cstdint>
#include <cstddef>

// ---------------------------------------------------------------------------
// GAT link predictor, fp32 baseline.
// Pipeline:
//   1. xw1 = x @ W1                     (gemm_xw_kernel)
//   2. alpha_s/alpha_d per node         (alpha_kernel<4>)
//   3. edge pass: agg += exp(lrelu(as[src]+ad[dst])) * xw[src], denom += ex
//      (atomics, self-loops included)   (edge_kernel<4>)
//   4. h = elu(agg/denom + b1)          (finalize_kernel<4,true>)
//   5..8. same for layer 2 (heads=1)    -> z
//   9. fused MLP over 800K pairs:
//      sigmoid(relu(relu([zi|zj]@mw1+mb1)@mw2+mb2)@mw3+mb3)  (mlp_kernel)
// Softmax max-subtraction is skipped (shift-invariant; logits are O(0.3)).
// ---------------------------------------------------------------------------

#define NEG_SLOPE 0.2f

// --- xw = x @ W  (n x 128) @ (128 x 128) -----------------------------------
__global__ __launch_bounds__(256) void gemm_xw_kernel(
    const float* __restrict__ x, const float* __restrict__ W,
    float* __restrict__ y, int n)
{
  __shared__ float sX[8][128];
  const int tid = threadIdx.x;
  const int rowblk = blockIdx.x * 8;
  {
    const int r = tid >> 5;
    const int c4 = (tid & 31) << 2;
    int row = rowblk + r;
    if (row >= n) row = n - 1;
    *(float4*)&sX[r][c4] = *(const float4*)&x[(size_t)row * 128 + c4];
  }
  __syncthreads();
  const int r = tid >> 5, tx = tid & 31;
  float4 acc = {0.f, 0.f, 0.f, 0.f};
  #pragma unroll 4
  for (int k = 0; k < 128; ++k) {
    const float xv = sX[r][k];
    const float4 w = *(const float4*)&W[k * 128 + tx * 4];
    acc.x += xv * w.x; acc.y += xv * w.y;
    acc.z += xv * w.z; acc.w += xv * w.w;
  }
  const int row = rowblk + r;
  if (row < n) *(float4*)&y[(size_t)row * 128 + tx * 4] = acc;
}

// --- per-node attention coefficients ---------------------------------------
// alpha_s[n][h] = sum_c xw[n][h*C+c] * a_src[h*C+c]   (one wave per node)
template<int HEADS>
__global__ __launch_bounds__(256) void alpha_kernel(
    const float* __restrict__ xw, const float* __restrict__ a_src,
    const float* __restrict__ a_dst, float* __restrict__ as_out,
    float* __restrict__ ad_out, int n)
{
  const int node = blockIdx.x * 4 + (threadIdx.x >> 6);
  const int lane = threadIdx.x & 63;
  if (node >= n) return;
  const float x1 = xw[(size_t)node * 128 + lane];
  const float x2 = xw[(size_t)node * 128 + lane + 64];
  float s1 = x1 * a_src[lane],      d1 = x1 * a_dst[lane];
  float s2 = x2 * a_src[lane + 64], d2 = x2 * a_dst[lane + 64];
  if (HEADS == 4) {
    // channels [0,32) -> head0 (lanes 0..31 partial s1), [32,64) -> head1,
    // [64,96) -> head2 (s2 of lanes 0..31), [96,128) -> head3.
    #pragma unroll
    for (int m = 1; m <= 16; m <<= 1) {
      s1 += __shfl_xor(s1, m); d1 += __shfl_xor(d1, m);
      s2 += __shfl_xor(s2, m); d2 += __shfl_xor(d2, m);
    }
    if (lane == 0) {
      as_out[node * 4 + 0] = s1; as_out[node * 4 + 2] = s2;
      ad_out[node * 4 + 0] = d1; ad_out[node * 4 + 2] = d2;
    } else if (lane == 32) {
      as_out[node * 4 + 1] = s1; as_out[node * 4 + 3] = s2;
      ad_out[node * 4 + 1] = d1; ad_out[node * 4 + 3] = d2;
    }
  } else {
    float s = s1 + s2, d = d1 + d2;
    #pragma unroll
    for (int m = 1; m <= 32; m <<= 1) {
      s += __shfl_xor(s, m); d += __shfl_xor(d, m);
    }
    if (lane == 0) { as_out[node] = s; ad_out[node] = d; }
  }
}

// --- edge pass: one wave per edge (incl. self-loops at the end) ------------
template<int HEADS>
__global__ __launch_bounds__(256) void edge_kernel(
    const int* __restrict__ ei,      // [2*E] : row0 = src, row1 = dst
    const float* __restrict__ xw,
    const float* __restrict__ as_, const float* __restrict__ ad_,
    float* __restrict__ agg, float* __restrict__ denom,
    int E, int n)
{
  const int wid = (int)((blockIdx.x * 256 + threadIdx.x) >> 6);
  const int lane = threadIdx.x & 63;
  const int total = E + n;
  if (wid >= total) return;
  int s, d;
  if (wid < E) { s = ei[wid]; d = ei[E + wid]; }
  else         { s = wid - E; d = s; }
  constexpr int C = 128 / HEADS;
  const int c0 = lane * 2;
  const int h = c0 / C;                     // same head for c0, c0+1
  float logit = as_[s * HEADS + h] + ad_[d * HEADS + h];
  logit = (logit > 0.f) ? logit : NEG_SLOPE * logit;
  const float ex = expf(logit);             // no max-subtraction (see header)
  const float2 xv = *(const float2*)&xw[(size_t)s * 128 + c0];
  atomicAdd(&agg[(size_t)d * 128 + c0],     ex * xv.x);
  atomicAdd(&agg[(size_t)d * 128 + c0 + 1], ex * xv.y);
  if ((c0 & (C - 1)) == 0) atomicAdd(&denom[d * HEADS + h], ex);
}

// --- finalize: y = act(agg/denom + bias) in place --------------------------
template<int HEADS, bool DO_ELU>
__global__ __launch_bounds__(256) void finalize_kernel(
    float* __restrict__ agg, const float* __restrict__ denom,
    const float* __restrict__ bias, int n)
{
  const int gid = blockIdx.x * 256 + threadIdx.x;
  const int node = gid >> 5;
  if (node >= n) return;
  const int c4 = (gid & 31) << 2;
  constexpr int CPERH = 128 / HEADS;
  float4 v = *(float4*)&agg[(size_t)node * 128 + c4];
  const int head = c4 / CPERH;              // all 4 lanes-channels same head
  const float inv = 1.f / denom[node * HEADS + head];
  const float4 bv = *(const float4*)&bias[c4];
  float r0 = v.x * inv + bv.x;
  float r1 = v.y * inv + bv.y;
  float r2 = v.z * inv + bv.z;
  float r3 = v.w * inv + bv.w;
  if (DO_ELU) {
    r0 = r0 > 0.f ? r0 : expm1f(r0);
    r1 = r1 > 0.f ? r1 : expm1f(r1);
    r2 = r2 > 0.f ? r2 : expm1f(r2);
    r3 = r3 > 0.f ? r3 : expm1f(r3);
  }
  float4 o = {r0, r1, r2, r3};
  *(float4*)&agg[(size_t)node * 128 + c4] = o;
}

// --- fused pair MLP: 64 pairs per block ------------------------------------
// L1: [64 x 256] @ [256 x 128] (K-chunked 64, A gathered from z)
// L2: [64 x 128] @ [128 x 64]
// L3: [64 x 64]  @ [64 x 1] -> sigmoid
__global__ __launch_bounds__(256) void mlp_kernel(
    const float* __restrict__ z, const int* __restrict__ pairs, // [2*P]
    const float* __restrict__ mw1, const float* __restrict__ mb1,
    const float* __restrict__ mw2, const float* __restrict__ mb2,
    const float* __restrict__ mw3, const float* __restrict__ mb3,
    float* __restrict__ out, int P)
{
  __shared__ int sI[64], sJ[64];
  __shared__ float sA[64][68];    // A-chunk | w2-chunk | h2
  __shared__ float sB[64][132];   // mw1-chunk | h1
  const int tid = threadIdx.x;
  const int pbase = blockIdx.x * 64;

  if (tid < 64) {
    int p = pbase + tid;
    sI[tid] = (p < P) ? pairs[p] : 0;
    sJ[tid] = (p < P) ? pairs[P + p] : 0;
  }
  __syncthreads();

  // ---- GEMM1: 64 pairs x 128 outs, K=256 ----
  const int ty = tid >> 5;   // 0..7 : rows ty*8 .. ty*8+7
  const int tx = tid & 31;   // cols tx*4 .. tx*4+3
  float acc[8][4];
  #pragma unroll
  for (int i = 0; i < 8; ++i)
    #pragma unroll
    for (int j = 0; j < 4; ++j) acc[i][j] = 0.f;

  for (int kc = 0; kc < 4; ++kc) {
    // stage A-chunk: e[p][kc*64+kk] ; kc<2 -> zi cols, kc>=2 -> zj cols
    #pragma unroll
    for (int i = 0; i < 16; ++i) {
      const int idx = tid + 256 * i;
      const int p = idx >> 6, kk = idx & 63;
      const int row = (kc < 2) ? sI[p] : sJ[p];
      const int col = ((kc & 1) << 6) + kk;
      sA[p][kk] = z[(size_t)row * 128 + col];
    }
    // stage B-chunk: mw1 rows kc*64..+63, all 128 cols
    #pragma unroll
    for (int i = 0; i < 32; ++i) {
      const int idx = tid + 256 * i;
      const int j = idx & 127, kk = idx >> 7;
      sB[kk][j] = mw1[(size_t)(kc * 64 + kk) * 128 + j];
    }
    __syncthreads();
    #pragma unroll 2
    for (int k = 0; k < 64; ++k) {
      const float4 b = *(const float4*)&sB[k][tx * 4];
      #pragma unroll
      for (int rr = 0; rr < 8; ++rr) {
        const float a = sA[ty * 8 + rr][k];
        acc[rr][0] += a * b.x; acc[rr][1] += a * b.y;
        acc[rr][2] += a * b.z; acc[rr][3] += a * b.w;
      }
    }
    __syncthreads();
  }
  // h1 = relu(acc + mb1) -> reuse sB slot
  {
    const float4 bv = *(const float4*)&mb1[tx * 4];
    #pragma unroll
    for (int rr = 0; rr < 8; ++rr) {
      const int r = ty * 8 + rr;
      sB[r][tx * 4 + 0] = fmaxf(acc[rr][0] + bv.x, 0.f);
      sB[r][tx * 4 + 1] = fmaxf(acc[rr][1] + bv.y, 0.f);
      sB[r][tx * 4 + 2] = fmaxf(acc[rr][2] + bv.z, 0.f);
      sB[r][tx * 4 + 3] = fmaxf(acc[rr][3] + bv.w, 0.f);
    }
  }
  __syncthreads();

  // ---- GEMM2: 64 pairs x 64 outs, K=128 ----
  const int ty2 = tid >> 4;  // 0..15 : rows ty2*4 .. +3
  const int tx2 = tid & 15;  // cols tx2*4 .. +3
  float acc2[4][4];
  #pragma unroll
  for (int i = 0; i < 4; ++i)
    #pragma unroll
    for (int j = 0; j < 4; ++j) acc2[i][j] = 0.f;

  for (int kc = 0; kc < 2; ++kc) {
    // stage w2 chunk into sA slot: rows kk = mw2 row kc*64+kk, 64 cols
    #pragma unroll
    for (int i = 0; i < 16; ++i) {
      const int idx = tid + 256 * i;
      const int j = idx & 63, kk = idx >> 6;
      sA[kk][j] = mw2[(size_t)(kc * 64 + kk) * 64 + j];
    }
    __syncthreads();
    #pragma unroll 2
    for (int k = 0; k < 64; ++k) {
      const float4 b = *(const float4*)&sA[k][tx2 * 4];
      #pragma unroll
      for (int rr = 0; rr < 4; ++rr) {
        const float a = sB[ty2 * 4 + rr][kc * 64 + k];   // h1
        acc2[rr][0] += a * b.x; acc2[rr][1] += a * b.y;
        acc2[rr][2] += a * b.z; acc2[rr][3] += a * b.w;
      }
    }
    __syncthreads();
  }
  // h2 = relu(acc2 + mb2) -> reuse sA slot
  {
    const float4 bv = *(const float4*)&mb2[tx2 * 4];
    #pragma unroll
    for (int rr = 0; rr < 4; ++rr) {
      const int r = ty2 * 4 + rr;
      sA[r][tx2 * 4 + 0] = fmaxf(acc2[rr][0] + bv.x, 0.f);
      sA[r][tx2 * 4 + 1] = fmaxf(acc2[rr][1] + bv.y, 0.f);
      sA[r][tx2 * 4 + 2] = fmaxf(acc2[rr][2] + bv.z, 0.f);
      sA[r][tx2 * 4 + 3] = fmaxf(acc2[rr][3] + bv.w, 0.f);
    }
  }
  __syncthreads();

  // ---- layer 3: out[p] = sigmoid(h2[p] . mw3 + mb3) ----
  {
    const int pl = tid >> 2, part = tid & 3;
    float sum = 0.f;
    #pragma unroll
    for (int c = 0; c < 16; ++c)
      sum += sA[pl][part * 16 + c] * mw3[part * 16 + c];
    sum += __shfl_xor(sum, 1);
    sum += __shfl_xor(sum, 2);
    if (part == 0) {
      const int p = pbase + pl;
      if (p < P) out[p] = 1.f / (1.f + expf(-(sum + mb3[0])));
    }
  }
}

// ---------------------------------------------------------------------------
extern "C" void kernel_launch(void* const* d_in, const int* in_sizes, int n_in,
                              void* d_out, int out_size, void* d_ws, size_t ws_size,
                              hipStream_t stream)
{
  const float* x   = (const float*)d_in[0];
  const int*   ei  = (const int*)d_in[1];
  const int*   ep  = (const int*)d_in[2];
  const float* W1  = (const float*)d_in[3];
  const float* as1 = (const float*)d_in[4];
  const float* ad1 = (const float*)d_in[5];
  const float* b1  = (const float*)d_in[6];
  const float* W2  = (const float*)d_in[7];
  const float* as2 = (const float*)d_in[8];
  const float* ad2 = (const float*)d_in[9];
  const float* b2  = (const float*)d_in[10];
  const float* mw1 = (const float*)d_in[11];
  const float* mb1 = (const float*)d_in[12];
  const float* mw2 = (const float*)d_in[13];
  const float* mb2 = (const float*)d_in[14];
  const float* mw3 = (const float*)d_in[15];
  const float* mb3 = (const float*)d_in[16];

  const int N = in_sizes[0] / 128;
  const int E = in_sizes[1] / 2;
  const int P = in_sizes[2] / 2;

  float* ws    = (float*)d_ws;
  float* xw    = ws;                        // N*128
  float* agg_h = xw    + (size_t)N * 128;   // N*128 (agg1 -> h)
  float* den1  = agg_h + (size_t)N * 128;   // N*4
  float* agg_z = den1  + (size_t)N * 4;     // N*128 (agg2 -> z)
  float* den2  = agg_z + (size_t)N * 128;   // N*4
  float* as_   = den2  + (size_t)N * 4;     // N*4
  float* ad_   = as_   + (size_t)N * 4;     // N*4
  float* out   = (float*)d_out;

  // zero the accumulators (agg + adjacent denom in one shot each)
  hipMemsetAsync(agg_h, 0, (size_t)N * 132 * sizeof(float), stream);
  hipMemsetAsync(agg_z, 0, (size_t)N * 132 * sizeof(float), stream);

  const int total_e = E + N;

  // ---- layer 1 (heads=4, C=32) ----
  gemm_xw_kernel<<<(N + 7) / 8, 256, 0, stream>>>(x, W1, xw, N);
  alpha_kernel<4><<<(N + 3) / 4, 256, 0, stream>>>(xw, as1, ad1, as_, ad_, N);
  edge_kernel<4><<<(total_e + 3) / 4, 256, 0, stream>>>(ei, xw, as_, ad_, agg_h, den1, E, N);
  finalize_kernel<4, true><<<(N * 32 + 255) / 256, 256, 0, stream>>>(agg_h, den1, b1, N);

  // ---- layer 2 (heads=1, C=128) ----
  gemm_xw_kernel<<<(N + 7) / 8, 256, 0, stream>>>(agg_h, W2, xw, N);
  alpha_kernel<1><<<(N + 3) / 4, 256, 0, stream>>>(xw, as2, ad2, as_, ad_, N);
  edge_kernel<1><<<(total_e + 3) / 4, 256, 0, stream>>>(ei, xw, as_, ad_, agg_z, den2, E, N);
  finalize_kernel<1, false><<<(N * 32 + 255) / 256, 256, 0, stream>>>(agg_z, den2, b2, N);

  // ---- fused pair MLP ----
  mlp_kernel<<<(P + 63) / 64, 256, 0, stream>>>(agg_z, ep, mw1, mb1, mw2, mb2,
                                                mw3, mb3, out, P);
}

// Round 3
// 917.392 us; speedup vs baseline: 3.8753x; 3.8753x over previous
//
#include <hip/hip_runtime.h>
#include <cstdint>
#include <cstddef>

// ---------------------------------------------------------------------------
// GAT link predictor, round 3.
//  - CSR built on device ONCE (shared by both GAT layers): hist -> scan ->
//    scatter. Edge aggregation = one wave per dst node, register accumulate,
//    fused normalize+bias+activation. No fp32 atomics, no agg memsets.
//  - Pair MLP on bf16 MFMA (16x16x32): z kept in bf16, mw1/mw2 preconverted
//    to transposed bf16 ([N][K] so each lane loads 8 contiguous k = 16B,
//    the m92/m97-verified B^T fragment pattern). fp32 accumulate + fp32 bias.
//  - Softmax max-subtraction skipped (shift-invariant; logits ~N(0,0.25)).
// ---------------------------------------------------------------------------

#define NEG_SLOPE 0.2f

typedef __bf16 bf16x8 __attribute__((ext_vector_type(8)));
typedef float  f32x4  __attribute__((ext_vector_type(4)));

// --- xw = x @ W  (n x 128) @ (128 x 128) -----------------------------------
__global__ __launch_bounds__(256) void gemm_xw_kernel(
    const float* __restrict__ x, const float* __restrict__ W,
    float* __restrict__ y, int n)
{
  __shared__ float sX[8][128];
  const int tid = threadIdx.x;
  const int rowblk = blockIdx.x * 8;
  {
    const int r = tid >> 5;
    const int c4 = (tid & 31) << 2;
    int row = rowblk + r;
    if (row >= n) row = n - 1;
    *(float4*)&sX[r][c4] = *(const float4*)&x[(size_t)row * 128 + c4];
  }
  __syncthreads();
  const int r = tid >> 5, tx = tid & 31;
  float4 acc = {0.f, 0.f, 0.f, 0.f};
  #pragma unroll 4
  for (int k = 0; k < 128; ++k) {
    const float xv = sX[r][k];
    const float4 w = *(const float4*)&W[k * 128 + tx * 4];
    acc.x += xv * w.x; acc.y += xv * w.y;
    acc.z += xv * w.z; acc.w += xv * w.w;
  }
  const int row = rowblk + r;
  if (row < n) *(float4*)&y[(size_t)row * 128 + tx * 4] = acc;
}

// --- per-node attention coefficients (unchanged, verified) -----------------
template<int HEADS>
__global__ __launch_bounds__(256) void alpha_kernel(
    const float* __restrict__ xw, const float* __restrict__ a_src,
    const float* __restrict__ a_dst, float* __restrict__ as_out,
    float* __restrict__ ad_out, int n)
{
  const int node = blockIdx.x * 4 + (threadIdx.x >> 6);
  const int lane = threadIdx.x & 63;
  if (node >= n) return;
  const float x1 = xw[(size_t)node * 128 + lane];
  const float x2 = xw[(size_t)node * 128 + lane + 64];
  float s1 = x1 * a_src[lane],      d1 = x1 * a_dst[lane];
  float s2 = x2 * a_src[lane + 64], d2 = x2 * a_dst[lane + 64];
  if (HEADS == 4) {
    #pragma unroll
    for (int m = 1; m <= 16; m <<= 1) {
      s1 += __shfl_xor(s1, m); d1 += __shfl_xor(d1, m);
      s2 += __shfl_xor(s2, m); d2 += __shfl_xor(d2, m);
    }
    if (lane == 0) {
      as_out[node * 4 + 0] = s1; as_out[node * 4 + 2] = s2;
      ad_out[node * 4 + 0] = d1; ad_out[node * 4 + 2] = d2;
    } else if (lane == 32) {
      as_out[node * 4 + 1] = s1; as_out[node * 4 + 3] = s2;
      ad_out[node * 4 + 1] = d1; ad_out[node * 4 + 3] = d2;
    }
  } else {
    float s = s1 + s2, d = d1 + d2;
    #pragma unroll
    for (int m = 1; m <= 32; m <<= 1) {
      s += __shfl_xor(s, m); d += __shfl_xor(d, m);
    }
    if (lane == 0) { as_out[node] = s; ad_out[node] = d; }
  }
}

// --- CSR build: histogram -> block scan -> scatter -------------------------
__global__ __launch_bounds__(256) void hist_kernel(
    const int* __restrict__ ei, int* __restrict__ deg, int E, int n)
{
  const int e = blockIdx.x * 256 + threadIdx.x;
  if (e >= E + n) return;
  const int d = (e < E) ? ei[E + e] : e - E;   // self-loops appended
  atomicAdd(&deg[d], 1);
}

__global__ __launch_bounds__(256) void scan1_kernel(
    const int* __restrict__ deg, int* __restrict__ part,
    int* __restrict__ bsum, int n)
{
  __shared__ int s[256];
  const int i = blockIdx.x * 256 + threadIdx.x;
  s[threadIdx.x] = (i < n) ? deg[i] : 0;
  __syncthreads();
  #pragma unroll
  for (int off = 1; off < 256; off <<= 1) {
    const int t = (threadIdx.x >= off) ? s[threadIdx.x - off] : 0;
    __syncthreads();
    s[threadIdx.x] += t;
    __syncthreads();
  }
  if (i < n) part[i] = s[threadIdx.x];
  if (threadIdx.x == 255) bsum[blockIdx.x] = s[255];
}

__global__ __launch_bounds__(256) void scan2_kernel(int* __restrict__ bsum, int nb)
{
  __shared__ int s[256];
  s[threadIdx.x] = (threadIdx.x < nb) ? bsum[threadIdx.x] : 0;
  __syncthreads();
  #pragma unroll
  for (int off = 1; off < 256; off <<= 1) {
    const int t = (threadIdx.x >= off) ? s[threadIdx.x - off] : 0;
    __syncthreads();
    s[threadIdx.x] += t;
    __syncthreads();
  }
  const int excl = (threadIdx.x == 0) ? 0 : s[threadIdx.x - 1];
  if (threadIdx.x < nb) bsum[threadIdx.x] = excl;
}

__global__ __launch_bounds__(256) void scan3_kernel(
    const int* __restrict__ part, const int* __restrict__ bsum,
    int* __restrict__ rowptr, int n)
{
  const int i = blockIdx.x * 256 + threadIdx.x;
  if (i < n) rowptr[i + 1] = part[i] + bsum[blockIdx.x];
  if (i == 0) rowptr[0] = 0;
}

__global__ __launch_bounds__(256) void fill_kernel(
    const int* __restrict__ ei, const int* __restrict__ rowptr,
    int* __restrict__ cur, int* __restrict__ csr_src, int E, int n)
{
  const int e = blockIdx.x * 256 + threadIdx.x;
  if (e >= E + n) return;
  int s, d;
  if (e < E) { s = ei[e]; d = ei[E + e]; }
  else       { s = e - E; d = s; }
  const int pos = rowptr[d] + atomicAdd(&cur[d], 1);
  csr_src[pos] = s;
}

// --- fused GAT aggregate: one wave per dst ---------------------------------
// agg = sum_s exp(lrelu(as[s]+ad[d])) * xw[s]; out = act(agg/den + bias)
template<int HEADS, bool DO_ELU, bool OUT_BF16>
__global__ __launch_bounds__(256) void gat_gather_kernel(
    const int* __restrict__ csr_src, const int* __restrict__ rowptr,
    const float* __restrict__ xw,
    const float* __restrict__ as_, const float* __restrict__ ad_,
    const float* __restrict__ bias,
    float* __restrict__ out_f32, __bf16* __restrict__ out_bf16, int n)
{
  const int d = blockIdx.x * 4 + (threadIdx.x >> 6);
  if (d >= n) return;
  const int lane = threadIdx.x & 63;
  const int c0 = lane * 2;
  constexpr int C = 128 / HEADS;
  const int head = c0 / C;
  const float ad_d = ad_[d * HEADS + head];
  const int r0 = rowptr[d], r1 = rowptr[d + 1];
  float accx = 0.f, accy = 0.f, den = 0.f;  // den identical across a head's lanes
  int s = (r0 < r1) ? csr_src[r0] : 0;
  for (int i = r0; i < r1; ++i) {
    const int s_next = (i + 1 < r1) ? csr_src[i + 1] : 0;  // prefetch
    float logit = as_[s * HEADS + head] + ad_d;
    logit = (logit > 0.f) ? logit : NEG_SLOPE * logit;
    const float ex = __expf(logit);
    const float2 v = *(const float2*)&xw[(size_t)s * 128 + c0];
    accx += ex * v.x; accy += ex * v.y; den += ex;
    s = s_next;
  }
  const float inv = 1.f / den;              // deg >= 1 (self-loop) -> no /0
  float rx = accx * inv + bias[c0];
  float ry = accy * inv + bias[c0 + 1];
  if (DO_ELU) {
    rx = rx > 0.f ? rx : expm1f(rx);
    ry = ry > 0.f ? ry : expm1f(ry);
  }
  if (OUT_BF16) {
    union { __bf16 b[2]; unsigned u; } pk;
    pk.b[0] = (__bf16)rx; pk.b[1] = (__bf16)ry;
    *(unsigned*)&out_bf16[(size_t)d * 128 + c0] = pk.u;
  } else {
    float2 o = {rx, ry};
    *(float2*)&out_f32[(size_t)d * 128 + c0] = o;
  }
}

// --- weight preconvert: w1t[n][k] = bf16(mw1[k][n]); w2t likewise ----------
__global__ __launch_bounds__(256) void convw_kernel(
    const float* __restrict__ mw1, const float* __restrict__ mw2,
    __bf16* __restrict__ w1t, __bf16* __restrict__ w2t)
{
  const int i = blockIdx.x * 256 + threadIdx.x;
  if (i < 128 * 256) {
    const int nn = i >> 8, k = i & 255;
    w1t[i] = (__bf16)mw1[k * 128 + nn];
  }
  if (i < 64 * 128) {
    const int nn = i >> 7, k = i & 127;
    w2t[i] = (__bf16)mw2[k * 64 + nn];
  }
}

// --- fused pair MLP on MFMA: 64 pairs/block, 4 waves -----------------------
// GEMM1 [64x256]@[256x128], GEMM2 [64x128]@[128x64], dot64 -> sigmoid.
// A-frags gathered straight from global z_bf (row-major, k-contiguous);
// B-frags from transposed bf16 weights (L1/L2 resident).
__global__ __launch_bounds__(256) void mlp_mfma_kernel(
    const __bf16* __restrict__ z, const int* __restrict__ pairs,
    const __bf16* __restrict__ w1t, const float* __restrict__ mb1,
    const __bf16* __restrict__ w2t, const float* __restrict__ mb2,
    const float* __restrict__ mw3, const float* __restrict__ mb3,
    float* __restrict__ out, int P)
{
  __shared__ int sIJ[128];                              // sI | sJ
  __shared__ __align__(16) __bf16 h1[64][136];          // pad: stride 272B
  __shared__ __align__(16) __bf16 h2[64][72];           // pad: stride 144B
  const int tid = threadIdx.x;
  const int wave = tid >> 6, lane = tid & 63;
  const int pbase = blockIdx.x * 64;
  if (tid < 64) {
    const int p = pbase + tid;
    sIJ[tid]      = (p < P) ? pairs[p]     : 0;
    sIJ[64 + tid] = (p < P) ? pairs[P + p] : 0;
  }
  __syncthreads();

  const int l16 = lane & 15;
  const int kl  = (lane >> 4) << 3;   // k-offset within frag: 0,8,16,24
  const int r4  = (lane >> 4) << 2;   // C/D row base: (lane>>4)*4

  // ---- GEMM1: wave tile 32(m) x 64(n); waves: m0=(w&1)*32, n0=(w>>1)*64 ----
  const int m0 = (wave & 1) * 32;
  const int n0 = (wave >> 1) * 64;
  const size_t zi0 = (size_t)sIJ[m0 + l16] * 128;
  const size_t zi1 = (size_t)sIJ[m0 + 16 + l16] * 128;
  const size_t zj0 = (size_t)sIJ[64 + m0 + l16] * 128;
  const size_t zj1 = (size_t)sIJ[64 + m0 + 16 + l16] * 128;

  f32x4 acc[2][4] = {};
  #pragma unroll
  for (int ks = 0; ks < 8; ++ks) {
    const int k0 = ks * 32;
    const int col = (k0 & 127) + kl;
    bf16x8 a0, a1;
    if (k0 < 128) { a0 = *(const bf16x8*)&z[zi0 + col];
                    a1 = *(const bf16x8*)&z[zi1 + col]; }
    else          { a0 = *(const bf16x8*)&z[zj0 + col];
                    a1 = *(const bf16x8*)&z[zj1 + col]; }
    #pragma unroll
    for (int ni = 0; ni < 4; ++ni) {
      const bf16x8 b = *(const bf16x8*)&w1t[(size_t)(n0 + ni * 16 + l16) * 256 + k0 + kl];
      acc[0][ni] = __builtin_amdgcn_mfma_f32_16x16x32_bf16(a0, b, acc[0][ni], 0, 0, 0);
      acc[1][ni] = __builtin_amdgcn_mfma_f32_16x16x32_bf16(a1, b, acc[1][ni], 0, 0, 0);
    }
  }
  // epilogue: bias + relu -> h1 (bf16). D layout: col=lane&15, row=r4+j (m89)
  #pragma unroll
  for (int ni = 0; ni < 4; ++ni) {
    const int colg = n0 + ni * 16 + l16;
    const float bv = mb1[colg];
    #pragma unroll
    for (int mi = 0; mi < 2; ++mi)
      #pragma unroll
      for (int j = 0; j < 4; ++j)
        h1[m0 + mi * 16 + r4 + j][colg] = (__bf16)fmaxf(acc[mi][ni][j] + bv, 0.f);
  }
  __syncthreads();

  // ---- GEMM2: wave tile 32 x 32; n0b=(w>>1)*32 ----
  const int n0b = (wave >> 1) * 32;
  f32x4 acc2[2][2] = {};
  #pragma unroll
  for (int ks = 0; ks < 4; ++ks) {
    const int k0 = ks * 32;
    const bf16x8 a0 = *(const bf16x8*)&h1[m0 + l16][k0 + kl];
    const bf16x8 a1 = *(const bf16x8*)&h1[m0 + 16 + l16][k0 + kl];
    #pragma unroll
    for (int ni = 0; ni < 2; ++ni) {
      const bf16x8 b = *(const bf16x8*)&w2t[(size_t)(n0b + ni * 16 + l16) * 128 + k0 + kl];
      acc2[0][ni] = __builtin_amdgcn_mfma_f32_16x16x32_bf16(a0, b, acc2[0][ni], 0, 0, 0);
      acc2[1][ni] = __builtin_amdgcn_mfma_f32_16x16x32_bf16(a1, b, acc2[1][ni], 0, 0, 0);
    }
  }
  #pragma unroll
  for (int ni = 0; ni < 2; ++ni) {
    const int colg = n0b + ni * 16 + l16;
    const float bv = mb2[colg];
    #pragma unroll
    for (int mi = 0; mi < 2; ++mi)
      #pragma unroll
      for (int j = 0; j < 4; ++j)
        h2[m0 + mi * 16 + r4 + j][colg] = (__bf16)fmaxf(acc2[mi][ni][j] + bv, 0.f);
  }
  __syncthreads();

  // ---- layer 3: out = sigmoid(h2 . mw3 + mb3), 4 threads/pair ----
  {
    const int pl = tid >> 2, part = tid & 3;
    const bf16x8 v0 = *(const bf16x8*)&h2[pl][part * 16];
    const bf16x8 v1 = *(const bf16x8*)&h2[pl][part * 16 + 8];
    float sum = 0.f;
    #pragma unroll
    for (int c = 0; c < 8; ++c) {
      sum += (float)v0[c] * mw3[part * 16 + c];
      sum += (float)v1[c] * mw3[part * 16 + 8 + c];
    }
    sum += __shfl_xor(sum, 1);
    sum += __shfl_xor(sum, 2);
    if (part == 0) {
      const int p = pbase + pl;
      if (p < P) out[p] = 1.f / (1.f + expf(-(sum + mb3[0])));
    }
  }
}

// ---------------------------------------------------------------------------
extern "C" void kernel_launch(void* const* d_in, const int* in_sizes, int n_in,
                              void* d_out, int out_size, void* d_ws, size_t ws_size,
                              hipStream_t stream)
{
  const float* x   = (const float*)d_in[0];
  const int*   ei  = (const int*)d_in[1];
  const int*   ep  = (const int*)d_in[2];
  const float* W1  = (const float*)d_in[3];
  const float* as1 = (const float*)d_in[4];
  const float* ad1 = (const float*)d_in[5];
  const float* b1  = (const float*)d_in[6];
  const float* W2  = (const float*)d_in[7];
  const float* as2 = (const float*)d_in[8];
  const float* ad2 = (const float*)d_in[9];
  const float* b2  = (const float*)d_in[10];
  const float* mw1 = (const float*)d_in[11];
  const float* mb1 = (const float*)d_in[12];
  const float* mw2 = (const float*)d_in[13];
  const float* mb2 = (const float*)d_in[14];
  const float* mw3 = (const float*)d_in[15];
  const float* mb3 = (const float*)d_in[16];

  const int N = in_sizes[0] / 128;
  const int E = in_sizes[1] / 2;
  const int P = in_sizes[2] / 2;
  const int EN = E + N;

  // ---- workspace carve-up ----
  float* ws   = (float*)d_ws;
  float* xw   = ws;                          // N*128 f32
  float* h    = xw  + (size_t)N * 128;       // N*128 f32
  float* as_  = h   + (size_t)N * 128;       // N*4
  float* ad_  = as_ + (size_t)N * 4;         // N*4
  __bf16* z_bf = (__bf16*)(ad_ + (size_t)N * 4);        // N*128 bf16
  __bf16* w1t  = z_bf + (size_t)N * 128;                // 128*256 bf16
  __bf16* w2t  = w1t + 128 * 256;                       // 64*128 bf16
  int* rowptr  = (int*)(w2t + 64 * 128);                // N+1
  int* deg     = rowptr + (N + 1);                      // N
  int* cur     = deg + N;                               // N
  int* part    = cur + N;                               // N
  int* bsum    = part + N;                              // 256
  int* csr_src = bsum + 256;                            // E+N
  float* out   = (float*)d_out;

  const int gEN = (EN + 255) / 256;
  const int nb  = (N + 255) / 256;           // 196 <= 256 (single-block scan2)

  // ---- CSR build (once; both layers share the graph) ----
  hipMemsetAsync(deg, 0, (size_t)2 * N * sizeof(int), stream);  // deg + cur
  hist_kernel <<<gEN, 256, 0, stream>>>(ei, deg, E, N);
  scan1_kernel<<<nb, 256, 0, stream>>>(deg, part, bsum, N);
  scan2_kernel<<<1, 256, 0, stream>>>(bsum, nb);
  scan3_kernel<<<nb, 256, 0, stream>>>(part, bsum, rowptr, N);
  fill_kernel <<<gEN, 256, 0, stream>>>(ei, rowptr, cur, csr_src, E, N);
  convw_kernel<<<128, 256, 0, stream>>>(mw1, mw2, w1t, w2t);

  // ---- layer 1 (heads=4) ----
  gemm_xw_kernel<<<(N + 7) / 8, 256, 0, stream>>>(x, W1, xw, N);
  alpha_kernel<4><<<(N + 3) / 4, 256, 0, stream>>>(xw, as1, ad1, as_, ad_, N);
  gat_gather_kernel<4, true, false><<<(N + 3) / 4, 256, 0, stream>>>(
      csr_src, rowptr, xw, as_, ad_, b1, h, nullptr, N);

  // ---- layer 2 (heads=1) -> z in bf16 ----
  gemm_xw_kernel<<<(N + 7) / 8, 256, 0, stream>>>(h, W2, xw, N);
  alpha_kernel<1><<<(N + 3) / 4, 256, 0, stream>>>(xw, as2, ad2, as_, ad_, N);
  gat_gather_kernel<1, false, true><<<(N + 3) / 4, 256, 0, stream>>>(
      csr_src, rowptr, xw, as_, ad_, b2, nullptr, z_bf, N);

  // ---- fused pair MLP (MFMA) ----
  mlp_mfma_kernel<<<(P + 63) / 64, 256, 0, stream>>>(
      z_bf, ep, w1t, mb1, w2t, mb2, mw3, mb3, out, P);
}

// Round 4
// 907.854 us; speedup vs baseline: 3.9160x; 1.0105x over previous
//
#include <hip/hip_runtime.h>
#include <cstdint>
#include <cstddef>

// ---------------------------------------------------------------------------
// GAT link predictor, round 4.
//  - CSR built on device once (both layers share the graph).
//  - xw stored bf16 -> halves the dominant edge-gather traffic.
//  - MLP layer 1 decomposed per-node: u = z@mw1[:128], v = z@mw1[128:],
//    h1(pair) = relu(u[i]+v[j]+mb1)  (52 GFLOP/pair-GEMM deleted).
//  - pair_kernel: LDS-free, register-resident MFMA for GEMM2, high occupancy
//    to hide the (inherent) 512 B/pair u/v gather latency.
//  - Softmax max-subtraction skipped (shift-invariant; logits ~N(0,0.25)).
// ---------------------------------------------------------------------------

#define NEG_SLOPE 0.2f

typedef __bf16 bf16x8 __attribute__((ext_vector_type(8)));
typedef float  f32x4  __attribute__((ext_vector_type(4)));

static __device__ __forceinline__ float bflo(unsigned pv) {
  return __uint_as_float(pv << 16);
}
static __device__ __forceinline__ float bfhi(unsigned pv) {
  return __uint_as_float(pv & 0xffff0000u);
}

// --- xw(bf16) = x(f32) @ W(f32), [n x 128] @ [128 x 128] -------------------
__global__ __launch_bounds__(256) void gemm_xw_kernel(
    const float* __restrict__ x, const float* __restrict__ W,
    __bf16* __restrict__ y, int n)
{
  __shared__ float sX[8][128];
  const int tid = threadIdx.x;
  const int rowblk = blockIdx.x * 8;
  {
    const int r = tid >> 5;
    const int c4 = (tid & 31) << 2;
    int row = rowblk + r;
    if (row >= n) row = n - 1;
    *(float4*)&sX[r][c4] = *(const float4*)&x[(size_t)row * 128 + c4];
  }
  __syncthreads();
  const int r = tid >> 5, tx = tid & 31;
  float4 acc = {0.f, 0.f, 0.f, 0.f};
  #pragma unroll 4
  for (int k = 0; k < 128; ++k) {
    const float xv = sX[r][k];
    const float4 w = *(const float4*)&W[k * 128 + tx * 4];
    acc.x += xv * w.x; acc.y += xv * w.y;
    acc.z += xv * w.z; acc.w += xv * w.w;
  }
  const int row = rowblk + r;
  if (row < n) {
    union { __bf16 b[4]; uint2 u2; } pk;
    pk.b[0] = (__bf16)acc.x; pk.b[1] = (__bf16)acc.y;
    pk.b[2] = (__bf16)acc.z; pk.b[3] = (__bf16)acc.w;
    *(uint2*)&y[(size_t)row * 128 + tx * 4] = pk.u2;
  }
}

// --- u,v (bf16) = z(f32) @ mw1[0:128,:], z @ mw1[128:256,:] ----------------
__global__ __launch_bounds__(256) void uv_kernel(
    const float* __restrict__ z, const float* __restrict__ mw1,
    __bf16* __restrict__ u, __bf16* __restrict__ v, int n)
{
  __shared__ float sZ[8][128];
  const int tid = threadIdx.x;
  const int rowblk = blockIdx.x * 8;
  {
    const int r = tid >> 5;
    const int c4 = (tid & 31) << 2;
    int row = rowblk + r;
    if (row >= n) row = n - 1;
    *(float4*)&sZ[r][c4] = *(const float4*)&z[(size_t)row * 128 + c4];
  }
  __syncthreads();
  const int r = tid >> 5, tx = tid & 31;
  float4 au = {0.f, 0.f, 0.f, 0.f};
  float4 av = {0.f, 0.f, 0.f, 0.f};
  #pragma unroll 2
  for (int k = 0; k < 128; ++k) {
    const float zv = sZ[r][k];
    const float4 wu = *(const float4*)&mw1[k * 128 + tx * 4];
    const float4 wv = *(const float4*)&mw1[(128 + k) * 128 + tx * 4];
    au.x += zv * wu.x; au.y += zv * wu.y; au.z += zv * wu.z; au.w += zv * wu.w;
    av.x += zv * wv.x; av.y += zv * wv.y; av.z += zv * wv.z; av.w += zv * wv.w;
  }
  const int row = rowblk + r;
  if (row < n) {
    union { __bf16 b[4]; uint2 u2; } pk;
    pk.b[0] = (__bf16)au.x; pk.b[1] = (__bf16)au.y;
    pk.b[2] = (__bf16)au.z; pk.b[3] = (__bf16)au.w;
    *(uint2*)&u[(size_t)row * 128 + tx * 4] = pk.u2;
    pk.b[0] = (__bf16)av.x; pk.b[1] = (__bf16)av.y;
    pk.b[2] = (__bf16)av.z; pk.b[3] = (__bf16)av.w;
    *(uint2*)&v[(size_t)row * 128 + tx * 4] = pk.u2;
  }
}

// --- per-node attention coefficients (xw now bf16) -------------------------
template<int HEADS>
__global__ __launch_bounds__(256) void alpha_kernel(
    const __bf16* __restrict__ xw, const float* __restrict__ a_src,
    const float* __restrict__ a_dst, float* __restrict__ as_out,
    float* __restrict__ ad_out, int n)
{
  const int node = blockIdx.x * 4 + (threadIdx.x >> 6);
  const int lane = threadIdx.x & 63;
  if (node >= n) return;
  const unsigned short* xwu = (const unsigned short*)xw;
  const float x1 = __uint_as_float((unsigned)xwu[(size_t)node * 128 + lane] << 16);
  const float x2 = __uint_as_float((unsigned)xwu[(size_t)node * 128 + lane + 64] << 16);
  float s1 = x1 * a_src[lane],      d1 = x1 * a_dst[lane];
  float s2 = x2 * a_src[lane + 64], d2 = x2 * a_dst[lane + 64];
  if (HEADS == 4) {
    #pragma unroll
    for (int m = 1; m <= 16; m <<= 1) {
      s1 += __shfl_xor(s1, m); d1 += __shfl_xor(d1, m);
      s2 += __shfl_xor(s2, m); d2 += __shfl_xor(d2, m);
    }
    if (lane == 0) {
      as_out[node * 4 + 0] = s1; as_out[node * 4 + 2] = s2;
      ad_out[node * 4 + 0] = d1; ad_out[node * 4 + 2] = d2;
    } else if (lane == 32) {
      as_out[node * 4 + 1] = s1; as_out[node * 4 + 3] = s2;
      ad_out[node * 4 + 1] = d1; ad_out[node * 4 + 3] = d2;
    }
  } else {
    float s = s1 + s2, d = d1 + d2;
    #pragma unroll
    for (int m = 1; m <= 32; m <<= 1) {
      s += __shfl_xor(s, m); d += __shfl_xor(d, m);
    }
    if (lane == 0) { as_out[node] = s; ad_out[node] = d; }
  }
}

// --- CSR build: histogram -> block scan -> scatter -------------------------
__global__ __launch_bounds__(256) void hist_kernel(
    const int* __restrict__ ei, int* __restrict__ deg, int E, int n)
{
  const int e = blockIdx.x * 256 + threadIdx.x;
  if (e >= E + n) return;
  const int d = (e < E) ? ei[E + e] : e - E;   // self-loops appended
  atomicAdd(&deg[d], 1);
}

__global__ __launch_bounds__(256) void scan1_kernel(
    const int* __restrict__ deg, int* __restrict__ part,
    int* __restrict__ bsum, int n)
{
  __shared__ int s[256];
  const int i = blockIdx.x * 256 + threadIdx.x;
  s[threadIdx.x] = (i < n) ? deg[i] : 0;
  __syncthreads();
  #pragma unroll
  for (int off = 1; off < 256; off <<= 1) {
    const int t = (threadIdx.x >= off) ? s[threadIdx.x - off] : 0;
    __syncthreads();
    s[threadIdx.x] += t;
    __syncthreads();
  }
  if (i < n) part[i] = s[threadIdx.x];
  if (threadIdx.x == 255) bsum[blockIdx.x] = s[255];
}

__global__ __launch_bounds__(256) void scan2_kernel(int* __restrict__ bsum, int nb)
{
  __shared__ int s[256];
  s[threadIdx.x] = (threadIdx.x < nb) ? bsum[threadIdx.x] : 0;
  __syncthreads();
  #pragma unroll
  for (int off = 1; off < 256; off <<= 1) {
    const int t = (threadIdx.x >= off) ? s[threadIdx.x - off] : 0;
    __syncthreads();
    s[threadIdx.x] += t;
    __syncthreads();
  }
  const int excl = (threadIdx.x == 0) ? 0 : s[threadIdx.x - 1];
  if (threadIdx.x < nb) bsum[threadIdx.x] = excl;
}

__global__ __launch_bounds__(256) void scan3_kernel(
    const int* __restrict__ part, const int* __restrict__ bsum,
    int* __restrict__ rowptr, int n)
{
  const int i = blockIdx.x * 256 + threadIdx.x;
  if (i < n) rowptr[i + 1] = part[i] + bsum[blockIdx.x];
  if (i == 0) rowptr[0] = 0;
}

__global__ __launch_bounds__(256) void fill_kernel(
    const int* __restrict__ ei, const int* __restrict__ rowptr,
    int* __restrict__ cur, int* __restrict__ csr_src, int E, int n)
{
  const int e = blockIdx.x * 256 + threadIdx.x;
  if (e >= E + n) return;
  int s, d;
  if (e < E) { s = ei[e]; d = ei[E + e]; }
  else       { s = e - E; d = s; }
  const int pos = rowptr[d] + atomicAdd(&cur[d], 1);
  csr_src[pos] = s;
}

// --- fused GAT aggregate: one wave per dst, bf16 xw gather -----------------
template<int HEADS, bool DO_ELU>
__global__ __launch_bounds__(256) void gat_gather_kernel(
    const int* __restrict__ csr_src, const int* __restrict__ rowptr,
    const __bf16* __restrict__ xw,
    const float* __restrict__ as_, const float* __restrict__ ad_,
    const float* __restrict__ bias,
    float* __restrict__ out, int n)
{
  const int d = blockIdx.x * 4 + (threadIdx.x >> 6);
  if (d >= n) return;
  const int lane = threadIdx.x & 63;
  const int c0 = lane * 2;
  constexpr int C = 128 / HEADS;
  const int head = c0 / C;
  const float ad_d = ad_[d * HEADS + head];
  const int r0 = rowptr[d], r1 = rowptr[d + 1];
  float accx = 0.f, accy = 0.f, den = 0.f;
  int s = (r0 < r1) ? csr_src[r0] : 0;
  for (int i = r0; i < r1; ++i) {
    const int s_next = (i + 1 < r1) ? csr_src[i + 1] : 0;  // prefetch
    float logit = as_[s * HEADS + head] + ad_d;
    logit = (logit > 0.f) ? logit : NEG_SLOPE * logit;
    const float ex = __expf(logit);
    const unsigned pv = *(const unsigned*)&xw[(size_t)s * 128 + c0];
    accx += ex * bflo(pv); accy += ex * bfhi(pv); den += ex;
    s = s_next;
  }
  const float inv = 1.f / den;              // deg >= 1 (self-loop) -> no /0
  float rx = accx * inv + bias[c0];
  float ry = accy * inv + bias[c0 + 1];
  if (DO_ELU) {
    rx = rx > 0.f ? rx : expm1f(rx);
    ry = ry > 0.f ? ry : expm1f(ry);
  }
  float2 o = {rx, ry};
  *(float2*)&out[(size_t)d * 128 + c0] = o;
}

// --- weight preconvert: w2t[n][k] = bf16(mw2[k][n]) ------------------------
__global__ __launch_bounds__(256) void convw_kernel(
    const float* __restrict__ mw2, __bf16* __restrict__ w2t)
{
  const int i = blockIdx.x * 256 + threadIdx.x;
  if (i < 64 * 128) {
    const int nn = i >> 7, k = i & 127;
    w2t[i] = (__bf16)mw2[k * 64 + nn];
  }
}

// --- pair MLP: h1 = relu(u[i]+v[j]+mb1) straight into MFMA A-frags ---------
// 16 pairs/wave, 4 waves/block (fully independent: no LDS, no barriers).
// GEMM2 [16x128]@[128x64] per wave on mfma_16x16x32_bf16; layer3 dot + sigmoid.
__global__ __launch_bounds__(256) void pair_kernel(
    const __bf16* __restrict__ u, const __bf16* __restrict__ v,
    const int* __restrict__ pairs,
    const float* __restrict__ mb1,
    const __bf16* __restrict__ w2t, const float* __restrict__ mb2,
    const float* __restrict__ mw3, const float* __restrict__ mb3,
    float* __restrict__ out, int P)
{
  const int tid = threadIdx.x;
  const int wave = tid >> 6, lane = tid & 63;
  const int l16 = lane & 15;
  const int kl  = (lane >> 4) << 3;   // k-offset in frag: 0,8,16,24
  const int r4  = (lane >> 4) << 2;   // C/D row base
  const int mbase = blockIdx.x * 64 + wave * 16;

  int p = mbase + l16;
  if (p >= P) p = P - 1;
  const size_t ib = (size_t)pairs[p] * 128;
  const size_t jb = (size_t)pairs[P + p] * 128;

  // h1 fragment: a[s] holds cols s*32 + kl + [0..8) of row l16
  bf16x8 a[4];
  #pragma unroll
  for (int s = 0; s < 4; ++s) {
    const bf16x8 uu = *(const bf16x8*)&u[ib + s * 32 + kl];
    const bf16x8 vv = *(const bf16x8*)&v[jb + s * 32 + kl];
    float bb[8];
    *(float4*)&bb[0] = *(const float4*)&mb1[s * 32 + kl];
    *(float4*)&bb[4] = *(const float4*)&mb1[s * 32 + kl + 4];
    #pragma unroll
    for (int e = 0; e < 8; ++e)
      a[s][e] = (__bf16)fmaxf((float)uu[e] + (float)vv[e] + bb[e], 0.f);
  }

  // GEMM2: 16(m) x 64(n) x 128(k)
  f32x4 acc[4] = {};
  #pragma unroll
  for (int ks = 0; ks < 4; ++ks) {
    #pragma unroll
    for (int ni = 0; ni < 4; ++ni) {
      const bf16x8 b = *(const bf16x8*)&w2t[(size_t)(ni * 16 + l16) * 128 + ks * 32 + kl];
      acc[ni] = __builtin_amdgcn_mfma_f32_16x16x32_bf16(a[ks], b, acc[ni], 0, 0, 0);
    }
  }

  // layer 3: relu(h2 + mb2) . mw3 ; D layout col=l16(+16ni), row=r4+j (m89)
  float sum0 = 0.f, sum1 = 0.f, sum2 = 0.f, sum3 = 0.f;
  #pragma unroll
  for (int ni = 0; ni < 4; ++ni) {
    const int col = ni * 16 + l16;
    const float b2 = mb2[col];
    const float w3 = mw3[col];
    sum0 += fmaxf(acc[ni][0] + b2, 0.f) * w3;
    sum1 += fmaxf(acc[ni][1] + b2, 0.f) * w3;
    sum2 += fmaxf(acc[ni][2] + b2, 0.f) * w3;
    sum3 += fmaxf(acc[ni][3] + b2, 0.f) * w3;
  }
  #pragma unroll
  for (int m = 1; m <= 8; m <<= 1) {        // reduce over the 16-lane group
    sum0 += __shfl_xor(sum0, m); sum1 += __shfl_xor(sum1, m);
    sum2 += __shfl_xor(sum2, m); sum3 += __shfl_xor(sum3, m);
  }
  if (l16 == 0) {
    const int p0 = mbase + r4;
    const float b3 = mb3[0];
    float4 o;
    o.x = 1.f / (1.f + expf(-(sum0 + b3)));
    o.y = 1.f / (1.f + expf(-(sum1 + b3)));
    o.z = 1.f / (1.f + expf(-(sum2 + b3)));
    o.w = 1.f / (1.f + expf(-(sum3 + b3)));
    if (p0 + 3 < P) {
      *(float4*)&out[p0] = o;
    } else {
      if (p0     < P) out[p0]     = o.x;
      if (p0 + 1 < P) out[p0 + 1] = o.y;
      if (p0 + 2 < P) out[p0 + 2] = o.z;
      if (p0 + 3 < P) out[p0 + 3] = o.w;
    }
  }
}

// ---------------------------------------------------------------------------
extern "C" void kernel_launch(void* const* d_in, const int* in_sizes, int n_in,
                              void* d_out, int out_size, void* d_ws, size_t ws_size,
                              hipStream_t stream)
{
  const float* x   = (const float*)d_in[0];
  const int*   ei  = (const int*)d_in[1];
  const int*   ep  = (const int*)d_in[2];
  const float* W1  = (const float*)d_in[3];
  const float* as1 = (const float*)d_in[4];
  const float* ad1 = (const float*)d_in[5];
  const float* b1  = (const float*)d_in[6];
  const float* W2  = (const float*)d_in[7];
  const float* as2 = (const float*)d_in[8];
  const float* ad2 = (const float*)d_in[9];
  const float* b2  = (const float*)d_in[10];
  const float* mw1 = (const float*)d_in[11];
  const float* mb1 = (const float*)d_in[12];
  const float* mw2 = (const float*)d_in[13];
  const float* mb2 = (const float*)d_in[14];
  const float* mw3 = (const float*)d_in[15];
  const float* mb3 = (const float*)d_in[16];

  const int N = in_sizes[0] / 128;
  const int E = in_sizes[1] / 2;
  const int P = in_sizes[2] / 2;
  const int EN = E + N;

  // ---- workspace carve-up (~70 MB) ----
  float*  nodef = (float*)d_ws;                        // N*128 f32 (h, then z)
  float*  as_   = nodef + (size_t)N * 128;             // N*4
  float*  ad_   = as_   + (size_t)N * 4;               // N*4
  __bf16* xw_bf = (__bf16*)(ad_ + (size_t)N * 4);      // N*128 bf16
  __bf16* u_bf  = xw_bf + (size_t)N * 128;             // N*128 bf16
  __bf16* v_bf  = u_bf  + (size_t)N * 128;             // N*128 bf16
  __bf16* w2t   = v_bf  + (size_t)N * 128;             // 64*128 bf16
  int* rowptr   = (int*)(w2t + 64 * 128);              // N+1
  int* deg      = rowptr + (N + 1);                    // N
  int* cur      = deg + N;                             // N
  int* part     = cur + N;                             // N
  int* bsum     = part + N;                            // 256
  int* csr_src  = bsum + 256;                          // E+N
  float* out    = (float*)d_out;

  const int gEN = (EN + 255) / 256;
  const int nb  = (N + 255) / 256;           // 196 <= 256 (single-block scan2)

  // ---- CSR build (once; both layers share the graph) ----
  hipMemsetAsync(deg, 0, (size_t)2 * N * sizeof(int), stream);  // deg + cur
  hist_kernel <<<gEN, 256, 0, stream>>>(ei, deg, E, N);
  scan1_kernel<<<nb, 256, 0, stream>>>(deg, part, bsum, N);
  scan2_kernel<<<1, 256, 0, stream>>>(bsum, nb);
  scan3_kernel<<<nb, 256, 0, stream>>>(part, bsum, rowptr, N);
  fill_kernel <<<gEN, 256, 0, stream>>>(ei, rowptr, cur, csr_src, E, N);
  convw_kernel<<<32, 256, 0, stream>>>(mw2, w2t);

  // ---- layer 1 (heads=4): x -> xw_bf -> h (nodef) ----
  gemm_xw_kernel<<<(N + 7) / 8, 256, 0, stream>>>(x, W1, xw_bf, N);
  alpha_kernel<4><<<(N + 3) / 4, 256, 0, stream>>>(xw_bf, as1, ad1, as_, ad_, N);
  gat_gather_kernel<4, true><<<(N + 3) / 4, 256, 0, stream>>>(
      csr_src, rowptr, xw_bf, as_, ad_, b1, nodef, N);

  // ---- layer 2 (heads=1): h -> xw_bf -> z (nodef, overwrites dead h) ----
  gemm_xw_kernel<<<(N + 7) / 8, 256, 0, stream>>>(nodef, W2, xw_bf, N);
  alpha_kernel<1><<<(N + 3) / 4, 256, 0, stream>>>(xw_bf, as2, ad2, as_, ad_, N);
  gat_gather_kernel<1, false><<<(N + 3) / 4, 256, 0, stream>>>(
      csr_src, rowptr, xw_bf, as_, ad_, b2, nodef, N);

  // ---- per-node MLP-layer-1 halves: u = z@mw1_top, v = z@mw1_bot ----
  uv_kernel<<<(N + 7) / 8, 256, 0, stream>>>(nodef, mw1, u_bf, v_bf, N);

  // ---- pair MLP (LDS-free, MFMA GEMM2) ----
  pair_kernel<<<(P + 63) / 64, 256, 0, stream>>>(
      u_bf, v_bf, ep, mb1, w2t, mb2, mw3, mb3, out, P);
}

// Round 6
// 600.843 us; speedup vs baseline: 5.9169x; 1.5110x over previous
//
#include <hip/hip_runtime.h>
#include <cstdint>
#include <cstddef>

// ---------------------------------------------------------------------------
// GAT link predictor, round 5 (resubmit; round-5 bench was an infra failure).
//  - All dense node-GEMMs (x@W1, h@W2, z@[mw1_u|mw1_v]) on bf16 MFMA with
//    pre-transposed bf16 weights: kills the L2 weight-streaming bottleneck
//    (round-4: 6.25 GB L2 traffic in uv_kernel alone -> ~50 MB).
//  - CSR built once; gathers read/write bf16 rows.
//  - pair MLP: h1 = relu(u[i]+v[j]+mb1) in registers -> MFMA GEMM2 -> dot.
//  - Softmax max-subtraction skipped (shift-invariant; logits ~N(0,0.25)).
// ---------------------------------------------------------------------------

#define NEG_SLOPE 0.2f

typedef __bf16 bf16x8 __attribute__((ext_vector_type(8)));
typedef float  f32x4  __attribute__((ext_vector_type(4)));

static __device__ __forceinline__ float bflo(unsigned pv) {
  return __uint_as_float(pv << 16);
}
static __device__ __forceinline__ float bfhi(unsigned pv) {
  return __uint_as_float(pv & 0xffff0000u);
}

// --- f32 -> bf16 (vectorized) ----------------------------------------------
__global__ __launch_bounds__(256) void cvt_bf16_kernel(
    const float* __restrict__ x, __bf16* __restrict__ y, int total)
{
  const int i = (blockIdx.x * 256 + threadIdx.x) * 4;
  if (i + 3 < total) {
    const float4 v = *(const float4*)&x[i];
    union { __bf16 b[4]; uint2 u2; } pk;
    pk.b[0] = (__bf16)v.x; pk.b[1] = (__bf16)v.y;
    pk.b[2] = (__bf16)v.z; pk.b[3] = (__bf16)v.w;
    *(uint2*)&y[i] = pk.u2;
  }
}

// --- weight preconvert/transpose to bf16 [NOUT][K] -------------------------
// W1t/W2t: [128][128]; mw1t: [256][128] (u-half | v-half); w2t: [64][128]
__global__ __launch_bounds__(256) void convw_kernel(
    const float* __restrict__ W1, const float* __restrict__ W2,
    const float* __restrict__ mw1, const float* __restrict__ mw2,
    __bf16* __restrict__ W1t, __bf16* __restrict__ W2t,
    __bf16* __restrict__ mw1t, __bf16* __restrict__ w2t)
{
  const int i = blockIdx.x * 256 + threadIdx.x;
  if (i < 16384) {
    const int nn = i >> 7, k = i & 127;
    W1t[i] = (__bf16)W1[k * 128 + nn];
    W2t[i] = (__bf16)W2[k * 128 + nn];
  }
  if (i < 32768) {
    const int j = i >> 7, k = i & 127;
    mw1t[i] = (__bf16)((j < 128) ? mw1[k * 128 + j]
                                 : mw1[(128 + k) * 128 + (j - 128)]);
  }
  if (i < 8192) {
    const int nn = i >> 7, k = i & 127;
    w2t[i] = (__bf16)mw2[k * 64 + nn];
  }
}

// --- node GEMM on MFMA: C[n][NOUT] = A[n][128] @ Wt^T ----------------------
// 32 rows/block, 4 waves each covering NOUT/4 output cols.
template<int NOUT>
__global__ __launch_bounds__(256) void nodegemm_kernel(
    const __bf16* __restrict__ A, const __bf16* __restrict__ Wt,
    __bf16* __restrict__ C, int n)
{
  constexpr int NT = NOUT / 64;           // 16-col tiles per wave (2 or 4)
  const int tid = threadIdx.x;
  const int wave = tid >> 6, lane = tid & 63;
  const int l16 = lane & 15;
  const int kl  = (lane >> 4) << 3;       // frag k-offset 0,8,16,24
  const int r4  = (lane >> 4) << 2;       // C/D row base
  const int n0  = wave * (NOUT / 4);
  const int rowbase = blockIdx.x * 32;

  bf16x8 a[2][4];
  #pragma unroll
  for (int mt = 0; mt < 2; ++mt) {
    int row = rowbase + mt * 16 + l16;
    if (row >= n) row = n - 1;
    const size_t rb = (size_t)row * 128;
    #pragma unroll
    for (int ks = 0; ks < 4; ++ks)
      a[mt][ks] = *(const bf16x8*)&A[rb + ks * 32 + kl];
  }
  f32x4 acc[2][NT];
  #pragma unroll
  for (int mt = 0; mt < 2; ++mt)
    #pragma unroll
    for (int nt = 0; nt < NT; ++nt) acc[mt][nt] = (f32x4){0.f, 0.f, 0.f, 0.f};

  #pragma unroll
  for (int ks = 0; ks < 4; ++ks) {
    #pragma unroll
    for (int nt = 0; nt < NT; ++nt) {
      const bf16x8 b =
          *(const bf16x8*)&Wt[(size_t)(n0 + nt * 16 + l16) * 128 + ks * 32 + kl];
      #pragma unroll
      for (int mt = 0; mt < 2; ++mt)
        acc[mt][nt] = __builtin_amdgcn_mfma_f32_16x16x32_bf16(
            a[mt][ks], b, acc[mt][nt], 0, 0, 0);
    }
  }
  // D layout: col = lane&15 (per 16-tile), row = (lane>>4)*4 + j   (m89)
  #pragma unroll
  for (int mt = 0; mt < 2; ++mt) {
    #pragma unroll
    for (int nt = 0; nt < NT; ++nt) {
      const int col = n0 + nt * 16 + l16;
      #pragma unroll
      for (int j = 0; j < 4; ++j) {
        const int row = rowbase + mt * 16 + r4 + j;
        if (row < n) C[(size_t)row * NOUT + col] = (__bf16)acc[mt][nt][j];
      }
    }
  }
}

// --- per-node attention coefficients (bf16 xw) -----------------------------
template<int HEADS>
__global__ __launch_bounds__(256) void alpha_kernel(
    const __bf16* __restrict__ xw, const float* __restrict__ a_src,
    const float* __restrict__ a_dst, float* __restrict__ as_out,
    float* __restrict__ ad_out, int n)
{
  const int node = blockIdx.x * 4 + (threadIdx.x >> 6);
  const int lane = threadIdx.x & 63;
  if (node >= n) return;
  const unsigned short* xwu = (const unsigned short*)xw;
  const float x1 = __uint_as_float((unsigned)xwu[(size_t)node * 128 + lane] << 16);
  const float x2 = __uint_as_float((unsigned)xwu[(size_t)node * 128 + lane + 64] << 16);
  float s1 = x1 * a_src[lane],      d1 = x1 * a_dst[lane];
  float s2 = x2 * a_src[lane + 64], d2 = x2 * a_dst[lane + 64];
  if (HEADS == 4) {
    #pragma unroll
    for (int m = 1; m <= 16; m <<= 1) {
      s1 += __shfl_xor(s1, m); d1 += __shfl_xor(d1, m);
      s2 += __shfl_xor(s2, m); d2 += __shfl_xor(d2, m);
    }
    if (lane == 0) {
      as_out[node * 4 + 0] = s1; as_out[node * 4 + 2] = s2;
      ad_out[node * 4 + 0] = d1; ad_out[node * 4 + 2] = d2;
    } else if (lane == 32) {
      as_out[node * 4 + 1] = s1; as_out[node * 4 + 3] = s2;
      ad_out[node * 4 + 1] = d1; ad_out[node * 4 + 3] = d2;
    }
  } else {
    float s = s1 + s2, d = d1 + d2;
    #pragma unroll
    for (int m = 1; m <= 32; m <<= 1) {
      s += __shfl_xor(s, m); d += __shfl_xor(d, m);
    }
    if (lane == 0) { as_out[node] = s; ad_out[node] = d; }
  }
}

// --- CSR build: histogram -> block scan -> scatter -------------------------
__global__ __launch_bounds__(256) void hist_kernel(
    const int* __restrict__ ei, int* __restrict__ deg, int E, int n)
{
  const int e = blockIdx.x * 256 + threadIdx.x;
  if (e >= E + n) return;
  const int d = (e < E) ? ei[E + e] : e - E;   // self-loops appended
  atomicAdd(&deg[d], 1);
}

__global__ __launch_bounds__(256) void scan1_kernel(
    const int* __restrict__ deg, int* __restrict__ part,
    int* __restrict__ bsum, int n)
{
  __shared__ int s[256];
  const int i = blockIdx.x * 256 + threadIdx.x;
  s[threadIdx.x] = (i < n) ? deg[i] : 0;
  __syncthreads();
  #pragma unroll
  for (int off = 1; off < 256; off <<= 1) {
    const int t = (threadIdx.x >= off) ? s[threadIdx.x - off] : 0;
    __syncthreads();
    s[threadIdx.x] += t;
    __syncthreads();
  }
  if (i < n) part[i] = s[threadIdx.x];
  if (threadIdx.x == 255) bsum[blockIdx.x] = s[255];
}

__global__ __launch_bounds__(256) void scan2_kernel(int* __restrict__ bsum, int nb)
{
  __shared__ int s[256];
  s[threadIdx.x] = (threadIdx.x < nb) ? bsum[threadIdx.x] : 0;
  __syncthreads();
  #pragma unroll
  for (int off = 1; off < 256; off <<= 1) {
    const int t = (threadIdx.x >= off) ? s[threadIdx.x - off] : 0;
    __syncthreads();
    s[threadIdx.x] += t;
    __syncthreads();
  }
  const int excl = (threadIdx.x == 0) ? 0 : s[threadIdx.x - 1];
  if (threadIdx.x < nb) bsum[threadIdx.x] = excl;
}

__global__ __launch_bounds__(256) void scan3_kernel(
    const int* __restrict__ part, const int* __restrict__ bsum,
    int* __restrict__ rowptr, int n)
{
  const int i = blockIdx.x * 256 + threadIdx.x;
  if (i < n) rowptr[i + 1] = part[i] + bsum[blockIdx.x];
  if (i == 0) rowptr[0] = 0;
}

__global__ __launch_bounds__(256) void fill_kernel(
    const int* __restrict__ ei, const int* __restrict__ rowptr,
    int* __restrict__ cur, int* __restrict__ csr_src, int E, int n)
{
  const int e = blockIdx.x * 256 + threadIdx.x;
  if (e >= E + n) return;
  int s, d;
  if (e < E) { s = ei[e]; d = ei[E + e]; }
  else       { s = e - E; d = s; }
  const int pos = rowptr[d] + atomicAdd(&cur[d], 1);
  csr_src[pos] = s;
}

// --- fused GAT aggregate: one wave per dst, bf16 in/out --------------------
template<int HEADS, bool DO_ELU>
__global__ __launch_bounds__(256) void gat_gather_kernel(
    const int* __restrict__ csr_src, const int* __restrict__ rowptr,
    const __bf16* __restrict__ xw,
    const float* __restrict__ as_, const float* __restrict__ ad_,
    const float* __restrict__ bias,
    __bf16* __restrict__ out, int n)
{
  const int d = blockIdx.x * 4 + (threadIdx.x >> 6);
  if (d >= n) return;
  const int lane = threadIdx.x & 63;
  const int c0 = lane * 2;
  constexpr int C = 128 / HEADS;
  const int head = c0 / C;
  const float ad_d = ad_[d * HEADS + head];
  const int r0 = rowptr[d], r1 = rowptr[d + 1];
  float accx = 0.f, accy = 0.f, den = 0.f;
  int s = (r0 < r1) ? csr_src[r0] : 0;
  for (int i = r0; i < r1; ++i) {
    const int s_next = (i + 1 < r1) ? csr_src[i + 1] : 0;  // prefetch
    float logit = as_[s * HEADS + head] + ad_d;
    logit = (logit > 0.f) ? logit : NEG_SLOPE * logit;
    const float ex = __expf(logit);
    const unsigned pv = *(const unsigned*)&xw[(size_t)s * 128 + c0];
    accx += ex * bflo(pv); accy += ex * bfhi(pv); den += ex;
    s = s_next;
  }
  const float inv = 1.f / den;              // deg >= 1 (self-loop) -> no /0
  float rx = accx * inv + bias[c0];
  float ry = accy * inv + bias[c0 + 1];
  if (DO_ELU) {
    rx = rx > 0.f ? rx : expm1f(rx);
    ry = ry > 0.f ? ry : expm1f(ry);
  }
  union { __bf16 b[2]; unsigned u; } pk;
  pk.b[0] = (__bf16)rx; pk.b[1] = (__bf16)ry;
  *(unsigned*)&out[(size_t)d * 128 + c0] = pk.u;
}

// --- pair MLP: h1 = relu(uv[i,:128]+uv[j,128:]+mb1) -> MFMA GEMM2 -> dot ---
// 16 pairs/wave, 4 waves/block, no LDS, no barriers.
__global__ __launch_bounds__(256) void pair_kernel(
    const __bf16* __restrict__ uv, const int* __restrict__ pairs,
    const float* __restrict__ mb1,
    const __bf16* __restrict__ w2t, const float* __restrict__ mb2,
    const float* __restrict__ mw3, const float* __restrict__ mb3,
    float* __restrict__ out, int P)
{
  const int tid = threadIdx.x;
  const int wave = tid >> 6, lane = tid & 63;
  const int l16 = lane & 15;
  const int kl  = (lane >> 4) << 3;
  const int r4  = (lane >> 4) << 2;
  const int mbase = blockIdx.x * 64 + wave * 16;

  int p = mbase + l16;
  if (p >= P) p = P - 1;
  const size_t ib = (size_t)pairs[p] * 256;
  const size_t jb = (size_t)pairs[P + p] * 256 + 128;

  bf16x8 a[4];
  #pragma unroll
  for (int s = 0; s < 4; ++s) {
    const bf16x8 uu = *(const bf16x8*)&uv[ib + s * 32 + kl];
    const bf16x8 vv = *(const bf16x8*)&uv[jb + s * 32 + kl];
    float bb[8];
    *(float4*)&bb[0] = *(const float4*)&mb1[s * 32 + kl];
    *(float4*)&bb[4] = *(const float4*)&mb1[s * 32 + kl + 4];
    #pragma unroll
    for (int e = 0; e < 8; ++e)
      a[s][e] = (__bf16)fmaxf((float)uu[e] + (float)vv[e] + bb[e], 0.f);
  }

  f32x4 acc[4] = {};
  #pragma unroll
  for (int ks = 0; ks < 4; ++ks) {
    #pragma unroll
    for (int ni = 0; ni < 4; ++ni) {
      const bf16x8 b = *(const bf16x8*)&w2t[(size_t)(ni * 16 + l16) * 128 + ks * 32 + kl];
      acc[ni] = __builtin_amdgcn_mfma_f32_16x16x32_bf16(a[ks], b, acc[ni], 0, 0, 0);
    }
  }

  float sum0 = 0.f, sum1 = 0.f, sum2 = 0.f, sum3 = 0.f;
  #pragma unroll
  for (int ni = 0; ni < 4; ++ni) {
    const int col = ni * 16 + l16;
    const float b2 = mb2[col];
    const float w3 = mw3[col];
    sum0 += fmaxf(acc[ni][0] + b2, 0.f) * w3;
    sum1 += fmaxf(acc[ni][1] + b2, 0.f) * w3;
    sum2 += fmaxf(acc[ni][2] + b2, 0.f) * w3;
    sum3 += fmaxf(acc[ni][3] + b2, 0.f) * w3;
  }
  #pragma unroll
  for (int m = 1; m <= 8; m <<= 1) {
    sum0 += __shfl_xor(sum0, m); sum1 += __shfl_xor(sum1, m);
    sum2 += __shfl_xor(sum2, m); sum3 += __shfl_xor(sum3, m);
  }
  if (l16 == 0) {
    const int p0 = mbase + r4;
    const float b3 = mb3[0];
    float4 o;
    o.x = 1.f / (1.f + expf(-(sum0 + b3)));
    o.y = 1.f / (1.f + expf(-(sum1 + b3)));
    o.z = 1.f / (1.f + expf(-(sum2 + b3)));
    o.w = 1.f / (1.f + expf(-(sum3 + b3)));
    if (p0 + 3 < P) {
      *(float4*)&out[p0] = o;
    } else {
      if (p0     < P) out[p0]     = o.x;
      if (p0 + 1 < P) out[p0 + 1] = o.y;
      if (p0 + 2 < P) out[p0 + 2] = o.z;
      if (p0 + 3 < P) out[p0 + 3] = o.w;
    }
  }
}

// ---------------------------------------------------------------------------
extern "C" void kernel_launch(void* const* d_in, const int* in_sizes, int n_in,
                              void* d_out, int out_size, void* d_ws, size_t ws_size,
                              hipStream_t stream)
{
  const float* x   = (const float*)d_in[0];
  const int*   ei  = (const int*)d_in[1];
  const int*   ep  = (const int*)d_in[2];
  const float* W1  = (const float*)d_in[3];
  const float* as1 = (const float*)d_in[4];
  const float* ad1 = (const float*)d_in[5];
  const float* b1  = (const float*)d_in[6];
  const float* W2  = (const float*)d_in[7];
  const float* as2 = (const float*)d_in[8];
  const float* ad2 = (const float*)d_in[9];
  const float* b2  = (const float*)d_in[10];
  const float* mw1 = (const float*)d_in[11];
  const float* mb1 = (const float*)d_in[12];
  const float* mw2 = (const float*)d_in[13];
  const float* mb2 = (const float*)d_in[14];
  const float* mw3 = (const float*)d_in[15];
  const float* mb3 = (const float*)d_in[16];

  const int N = in_sizes[0] / 128;
  const int E = in_sizes[1] / 2;
  const int P = in_sizes[2] / 2;
  const int EN = E + N;

  // ---- workspace carve-up (~70 MB) ----
  __bf16* x_bf  = (__bf16*)d_ws;                       // N*128 (later: z_bf)
  __bf16* xw_bf = x_bf  + (size_t)N * 128;             // N*128
  __bf16* h_bf  = xw_bf + (size_t)N * 128;             // N*128
  __bf16* uv_bf = h_bf  + (size_t)N * 128;             // N*256
  __bf16* W1t   = uv_bf + (size_t)N * 256;             // 128*128
  __bf16* W2t   = W1t + 16384;                         // 128*128
  __bf16* mw1t  = W2t + 16384;                         // 256*128
  __bf16* w2t   = mw1t + 32768;                        // 64*128
  float*  as_   = (float*)(w2t + 8192);                // N*4
  float*  ad_   = as_ + (size_t)N * 4;                 // N*4
  int* rowptr   = (int*)(ad_ + (size_t)N * 4);         // N+1
  int* deg      = rowptr + (N + 1);                    // N
  int* cur      = deg + N;                             // N
  int* part     = cur + N;                             // N
  int* bsum     = part + N;                            // 256
  int* csr_src  = bsum + 256;                          // E+N
  __bf16* z_bf  = x_bf;                                // alias (x_bf dead by then)
  float* out    = (float*)d_out;

  const int gEN = (EN + 255) / 256;
  const int nb  = (N + 255) / 256;           // 196 <= 256 (single-block scan2)
  const int gNG = (N + 31) / 32;

  // ---- CSR build (once; both layers share the graph) ----
  hipMemsetAsync(deg, 0, (size_t)2 * N * sizeof(int), stream);  // deg + cur
  hist_kernel <<<gEN, 256, 0, stream>>>(ei, deg, E, N);
  scan1_kernel<<<nb, 256, 0, stream>>>(deg, part, bsum, N);
  scan2_kernel<<<1, 256, 0, stream>>>(bsum, nb);
  scan3_kernel<<<nb, 256, 0, stream>>>(part, bsum, rowptr, N);
  fill_kernel <<<gEN, 256, 0, stream>>>(ei, rowptr, cur, csr_src, E, N);
  convw_kernel<<<128, 256, 0, stream>>>(W1, W2, mw1, mw2, W1t, W2t, mw1t, w2t);
  cvt_bf16_kernel<<<(N * 128 / 4 + 255) / 256, 256, 0, stream>>>(x, x_bf, N * 128);

  // ---- layer 1 (heads=4): x_bf -> xw_bf -> h_bf ----
  nodegemm_kernel<128><<<gNG, 256, 0, stream>>>(x_bf, W1t, xw_bf, N);
  alpha_kernel<4><<<(N + 3) / 4, 256, 0, stream>>>(xw_bf, as1, ad1, as_, ad_, N);
  gat_gather_kernel<4, true><<<(N + 3) / 4, 256, 0, stream>>>(
      csr_src, rowptr, xw_bf, as_, ad_, b1, h_bf, N);

  // ---- layer 2 (heads=1): h_bf -> xw_bf -> z_bf (aliases x_bf) ----
  nodegemm_kernel<128><<<gNG, 256, 0, stream>>>(h_bf, W2t, xw_bf, N);
  alpha_kernel<1><<<(N + 3) / 4, 256, 0, stream>>>(xw_bf, as2, ad2, as_, ad_, N);
  gat_gather_kernel<1, false><<<(N + 3) / 4, 256, 0, stream>>>(
      csr_src, rowptr, xw_bf, as_, ad_, b2, z_bf, N);

  // ---- uv = z @ [mw1_u | mw1_v]  (per-node MLP layer-1 halves) ----
  nodegemm_kernel<256><<<gNG, 256, 0, stream>>>(z_bf, mw1t, uv_bf, N);

  // ---- pair MLP (LDS-free, MFMA GEMM2) ----
  pair_kernel<<<(P + 63) / 64, 256, 0, stream>>>(
      uv_bf, ep, mb1, w2t, mb2, mw3, mb3, out, P);
}

// Round 7
// 471.524 us; speedup vs baseline: 7.5397x; 1.2743x over previous
//
#include <hip/hip_runtime.h>
#include <cstdint>
#include <cstddef>

// ---------------------------------------------------------------------------
// GAT link predictor, round 7.
//  - round-6 profile: gat_gather x2 (~150us each) + pair_kernel (153us) are
//    random-row-gather LATENCY bound (218-410 MB logical vs L2/L3 us-scale).
//  - This round: 4-way edge unroll in gat_gather (4 independent load chains
//    in flight), 2-tile pair_kernel (2x in-flight loads, B-frag reuse).
//  - Dense GEMMs stay on bf16 MFMA (round-6 win). CSR built once.
//  - Softmax max-subtraction skipped (shift-invariant; logits ~N(0,0.25)).
// ---------------------------------------------------------------------------

#define NEG_SLOPE 0.2f

typedef __bf16 bf16x8 __attribute__((ext_vector_type(8)));
typedef float  f32x4  __attribute__((ext_vector_type(4)));

static __device__ __forceinline__ float bflo(unsigned pv) {
  return __uint_as_float(pv << 16);
}
static __device__ __forceinline__ float bfhi(unsigned pv) {
  return __uint_as_float(pv & 0xffff0000u);
}

// --- f32 -> bf16 (vectorized) ----------------------------------------------
__global__ __launch_bounds__(256) void cvt_bf16_kernel(
    const float* __restrict__ x, __bf16* __restrict__ y, int total)
{
  const int i = (blockIdx.x * 256 + threadIdx.x) * 4;
  if (i + 3 < total) {
    const float4 v = *(const float4*)&x[i];
    union { __bf16 b[4]; uint2 u2; } pk;
    pk.b[0] = (__bf16)v.x; pk.b[1] = (__bf16)v.y;
    pk.b[2] = (__bf16)v.z; pk.b[3] = (__bf16)v.w;
    *(uint2*)&y[i] = pk.u2;
  }
}

// --- weight preconvert/transpose to bf16 [NOUT][K] -------------------------
__global__ __launch_bounds__(256) void convw_kernel(
    const float* __restrict__ W1, const float* __restrict__ W2,
    const float* __restrict__ mw1, const float* __restrict__ mw2,
    __bf16* __restrict__ W1t, __bf16* __restrict__ W2t,
    __bf16* __restrict__ mw1t, __bf16* __restrict__ w2t)
{
  const int i = blockIdx.x * 256 + threadIdx.x;
  if (i < 16384) {
    const int nn = i >> 7, k = i & 127;
    W1t[i] = (__bf16)W1[k * 128 + nn];
    W2t[i] = (__bf16)W2[k * 128 + nn];
  }
  if (i < 32768) {
    const int j = i >> 7, k = i & 127;
    mw1t[i] = (__bf16)((j < 128) ? mw1[k * 128 + j]
                                 : mw1[(128 + k) * 128 + (j - 128)]);
  }
  if (i < 8192) {
    const int nn = i >> 7, k = i & 127;
    w2t[i] = (__bf16)mw2[k * 64 + nn];
  }
}

// --- node GEMM on MFMA: C[n][NOUT] = A[n][128] @ Wt^T ----------------------
template<int NOUT>
__global__ __launch_bounds__(256) void nodegemm_kernel(
    const __bf16* __restrict__ A, const __bf16* __restrict__ Wt,
    __bf16* __restrict__ C, int n)
{
  constexpr int NT = NOUT / 64;
  const int tid = threadIdx.x;
  const int wave = tid >> 6, lane = tid & 63;
  const int l16 = lane & 15;
  const int kl  = (lane >> 4) << 3;
  const int r4  = (lane >> 4) << 2;
  const int n0  = wave * (NOUT / 4);
  const int rowbase = blockIdx.x * 32;

  bf16x8 a[2][4];
  #pragma unroll
  for (int mt = 0; mt < 2; ++mt) {
    int row = rowbase + mt * 16 + l16;
    if (row >= n) row = n - 1;
    const size_t rb = (size_t)row * 128;
    #pragma unroll
    for (int ks = 0; ks < 4; ++ks)
      a[mt][ks] = *(const bf16x8*)&A[rb + ks * 32 + kl];
  }
  f32x4 acc[2][NT];
  #pragma unroll
  for (int mt = 0; mt < 2; ++mt)
    #pragma unroll
    for (int nt = 0; nt < NT; ++nt) acc[mt][nt] = (f32x4){0.f, 0.f, 0.f, 0.f};

  #pragma unroll
  for (int ks = 0; ks < 4; ++ks) {
    #pragma unroll
    for (int nt = 0; nt < NT; ++nt) {
      const bf16x8 b =
          *(const bf16x8*)&Wt[(size_t)(n0 + nt * 16 + l16) * 128 + ks * 32 + kl];
      #pragma unroll
      for (int mt = 0; mt < 2; ++mt)
        acc[mt][nt] = __builtin_amdgcn_mfma_f32_16x16x32_bf16(
            a[mt][ks], b, acc[mt][nt], 0, 0, 0);
    }
  }
  // D layout: col = lane&15 (per 16-tile), row = (lane>>4)*4 + j   (m89)
  #pragma unroll
  for (int mt = 0; mt < 2; ++mt) {
    #pragma unroll
    for (int nt = 0; nt < NT; ++nt) {
      const int col = n0 + nt * 16 + l16;
      #pragma unroll
      for (int j = 0; j < 4; ++j) {
        const int row = rowbase + mt * 16 + r4 + j;
        if (row < n) C[(size_t)row * NOUT + col] = (__bf16)acc[mt][nt][j];
      }
    }
  }
}

// --- per-node attention coefficients (bf16 xw) -----------------------------
template<int HEADS>
__global__ __launch_bounds__(256) void alpha_kernel(
    const __bf16* __restrict__ xw, const float* __restrict__ a_src,
    const float* __restrict__ a_dst, float* __restrict__ as_out,
    float* __restrict__ ad_out, int n)
{
  const int node = blockIdx.x * 4 + (threadIdx.x >> 6);
  const int lane = threadIdx.x & 63;
  if (node >= n) return;
  const unsigned short* xwu = (const unsigned short*)xw;
  const float x1 = __uint_as_float((unsigned)xwu[(size_t)node * 128 + lane] << 16);
  const float x2 = __uint_as_float((unsigned)xwu[(size_t)node * 128 + lane + 64] << 16);
  float s1 = x1 * a_src[lane],      d1 = x1 * a_dst[lane];
  float s2 = x2 * a_src[lane + 64], d2 = x2 * a_dst[lane + 64];
  if (HEADS == 4) {
    #pragma unroll
    for (int m = 1; m <= 16; m <<= 1) {
      s1 += __shfl_xor(s1, m); d1 += __shfl_xor(d1, m);
      s2 += __shfl_xor(s2, m); d2 += __shfl_xor(d2, m);
    }
    if (lane == 0) {
      as_out[node * 4 + 0] = s1; as_out[node * 4 + 2] = s2;
      ad_out[node * 4 + 0] = d1; ad_out[node * 4 + 2] = d2;
    } else if (lane == 32) {
      as_out[node * 4 + 1] = s1; as_out[node * 4 + 3] = s2;
      ad_out[node * 4 + 1] = d1; ad_out[node * 4 + 3] = d2;
    }
  } else {
    float s = s1 + s2, d = d1 + d2;
    #pragma unroll
    for (int m = 1; m <= 32; m <<= 1) {
      s += __shfl_xor(s, m); d += __shfl_xor(d, m);
    }
    if (lane == 0) { as_out[node] = s; ad_out[node] = d; }
  }
}

// --- CSR build: histogram -> block scan -> scatter -------------------------
__global__ __launch_bounds__(256) void hist_kernel(
    const int* __restrict__ ei, int* __restrict__ deg, int E, int n)
{
  const int e = blockIdx.x * 256 + threadIdx.x;
  if (e >= E + n) return;
  const int d = (e < E) ? ei[E + e] : e - E;   // self-loops appended
  atomicAdd(&deg[d], 1);
}

__global__ __launch_bounds__(256) void scan1_kernel(
    const int* __restrict__ deg, int* __restrict__ part,
    int* __restrict__ bsum, int n)
{
  __shared__ int s[256];
  const int i = blockIdx.x * 256 + threadIdx.x;
  s[threadIdx.x] = (i < n) ? deg[i] : 0;
  __syncthreads();
  #pragma unroll
  for (int off = 1; off < 256; off <<= 1) {
    const int t = (threadIdx.x >= off) ? s[threadIdx.x - off] : 0;
    __syncthreads();
    s[threadIdx.x] += t;
    __syncthreads();
  }
  if (i < n) part[i] = s[threadIdx.x];
  if (threadIdx.x == 255) bsum[blockIdx.x] = s[255];
}

__global__ __launch_bounds__(256) void scan2_kernel(int* __restrict__ bsum, int nb)
{
  __shared__ int s[256];
  s[threadIdx.x] = (threadIdx.x < nb) ? bsum[threadIdx.x] : 0;
  __syncthreads();
  #pragma unroll
  for (int off = 1; off < 256; off <<= 1) {
    const int t = (threadIdx.x >= off) ? s[threadIdx.x - off] : 0;
    __syncthreads();
    s[threadIdx.x] += t;
    __syncthreads();
  }
  const int excl = (threadIdx.x == 0) ? 0 : s[threadIdx.x - 1];
  if (threadIdx.x < nb) bsum[threadIdx.x] = excl;
}

__global__ __launch_bounds__(256) void scan3_kernel(
    const int* __restrict__ part, const int* __restrict__ bsum,
    int* __restrict__ rowptr, int n)
{
  const int i = blockIdx.x * 256 + threadIdx.x;
  if (i < n) rowptr[i + 1] = part[i] + bsum[blockIdx.x];
  if (i == 0) rowptr[0] = 0;
}

__global__ __launch_bounds__(256) void fill_kernel(
    const int* __restrict__ ei, const int* __restrict__ rowptr,
    int* __restrict__ cur, int* __restrict__ csr_src, int E, int n)
{
  const int e = blockIdx.x * 256 + threadIdx.x;
  if (e >= E + n) return;
  int s, d;
  if (e < E) { s = ei[e]; d = ei[E + e]; }
  else       { s = e - E; d = s; }
  const int pos = rowptr[d] + atomicAdd(&cur[d], 1);
  csr_src[pos] = s;
}

// --- fused GAT aggregate: one wave per dst, 4-way edge unroll --------------
template<int HEADS, bool DO_ELU>
__global__ __launch_bounds__(256) void gat_gather_kernel(
    const int* __restrict__ csr_src, const int* __restrict__ rowptr,
    const __bf16* __restrict__ xw,
    const float* __restrict__ as_, const float* __restrict__ ad_,
    const float* __restrict__ bias,
    __bf16* __restrict__ out, int n)
{
  const int d = blockIdx.x * 4 + (threadIdx.x >> 6);
  if (d >= n) return;
  const int lane = threadIdx.x & 63;
  const int c0 = lane * 2;
  constexpr int C = 128 / HEADS;
  const int head = c0 / C;
  const float ad_d = ad_[d * HEADS + head];
  const int r0 = rowptr[d], r1 = rowptr[d + 1];
  float accx = 0.f, accy = 0.f, den = 0.f;

  int i = r0;
  for (; i + 4 <= r1; i += 4) {
    int s[4];
    #pragma unroll
    for (int u = 0; u < 4; ++u) s[u] = csr_src[i + u];
    float lg[4]; unsigned pv[4];
    #pragma unroll
    for (int u = 0; u < 4; ++u) {          // 8 independent loads in flight
      lg[u] = as_[s[u] * HEADS + head];
      pv[u] = *(const unsigned*)&xw[(size_t)s[u] * 128 + c0];
    }
    #pragma unroll
    for (int u = 0; u < 4; ++u) {
      float l = lg[u] + ad_d;
      l = (l > 0.f) ? l : NEG_SLOPE * l;
      const float ex = __expf(l);
      accx += ex * bflo(pv[u]); accy += ex * bfhi(pv[u]); den += ex;
    }
  }
  for (; i < r1; ++i) {                    // tail
    const int s = csr_src[i];
    float l = as_[s * HEADS + head] + ad_d;
    l = (l > 0.f) ? l : NEG_SLOPE * l;
    const float ex = __expf(l);
    const unsigned pv = *(const unsigned*)&xw[(size_t)s * 128 + c0];
    accx += ex * bflo(pv); accy += ex * bfhi(pv); den += ex;
  }

  const float inv = 1.f / den;              // deg >= 1 (self-loop) -> no /0
  float rx = accx * inv + bias[c0];
  float ry = accy * inv + bias[c0 + 1];
  if (DO_ELU) {
    rx = rx > 0.f ? rx : expm1f(rx);
    ry = ry > 0.f ? ry : expm1f(ry);
  }
  union { __bf16 b[2]; unsigned u; } pk;
  pk.b[0] = (__bf16)rx; pk.b[1] = (__bf16)ry;
  *(unsigned*)&out[(size_t)d * 128 + c0] = pk.u;
}

// --- pair MLP: 2 m-tiles/wave (32 pairs), 128 pairs/block ------------------
// h1 = relu(uv[i,:128]+uv[j,128:]+mb1) in regs -> MFMA GEMM2 (B-frag shared
// across both tiles) -> dot64 -> sigmoid. No LDS, no barriers.
__global__ __launch_bounds__(256) void pair_kernel(
    const __bf16* __restrict__ uv, const int* __restrict__ pairs,
    const float* __restrict__ mb1,
    const __bf16* __restrict__ w2t, const float* __restrict__ mb2,
    const float* __restrict__ mw3, const float* __restrict__ mb3,
    float* __restrict__ out, int P)
{
  const int tid = threadIdx.x;
  const int wave = tid >> 6, lane = tid & 63;
  const int l16 = lane & 15;
  const int kl  = (lane >> 4) << 3;
  const int r4  = (lane >> 4) << 2;
  const int mbase = blockIdx.x * 128 + wave * 32;

  size_t ib[2], jb[2];
  #pragma unroll
  for (int t = 0; t < 2; ++t) {
    int p = mbase + t * 16 + l16;
    if (p >= P) p = P - 1;
    ib[t] = (size_t)pairs[p] * 256;
    jb[t] = (size_t)pairs[P + p] * 256 + 128;
  }

  // build both tiles' A-fragments (16 independent 16B loads in flight)
  bf16x8 a[2][4];
  #pragma unroll
  for (int t = 0; t < 2; ++t) {
    bf16x8 uu[4], vv[4];
    #pragma unroll
    for (int s = 0; s < 4; ++s) {
      uu[s] = *(const bf16x8*)&uv[ib[t] + s * 32 + kl];
      vv[s] = *(const bf16x8*)&uv[jb[t] + s * 32 + kl];
    }
    #pragma unroll
    for (int s = 0; s < 4; ++s) {
      float bb[8];
      *(float4*)&bb[0] = *(const float4*)&mb1[s * 32 + kl];
      *(float4*)&bb[4] = *(const float4*)&mb1[s * 32 + kl + 4];
      #pragma unroll
      for (int e = 0; e < 8; ++e)
        a[t][s][e] = (__bf16)fmaxf((float)uu[s][e] + (float)vv[s][e] + bb[e], 0.f);
    }
  }

  f32x4 acc[2][4] = {};
  #pragma unroll
  for (int ks = 0; ks < 4; ++ks) {
    #pragma unroll
    for (int ni = 0; ni < 4; ++ni) {
      const bf16x8 b = *(const bf16x8*)&w2t[(size_t)(ni * 16 + l16) * 128 + ks * 32 + kl];
      #pragma unroll
      for (int t = 0; t < 2; ++t)        // B-frag reused by both tiles
        acc[t][ni] = __builtin_amdgcn_mfma_f32_16x16x32_bf16(
            a[t][ks], b, acc[t][ni], 0, 0, 0);
    }
  }

  #pragma unroll
  for (int t = 0; t < 2; ++t) {
    float sum[4] = {0.f, 0.f, 0.f, 0.f};
    #pragma unroll
    for (int ni = 0; ni < 4; ++ni) {
      const int col = ni * 16 + l16;
      const float b2 = mb2[col];
      const float w3 = mw3[col];
      #pragma unroll
      for (int j = 0; j < 4; ++j)
        sum[j] += fmaxf(acc[t][ni][j] + b2, 0.f) * w3;
    }
    #pragma unroll
    for (int m = 1; m <= 8; m <<= 1) {
      #pragma unroll
      for (int j = 0; j < 4; ++j) sum[j] += __shfl_xor(sum[j], m);
    }
    if (l16 == 0) {
      const int p0 = mbase + t * 16 + r4;
      const float b3 = mb3[0];
      float4 o;
      o.x = 1.f / (1.f + expf(-(sum[0] + b3)));
      o.y = 1.f / (1.f + expf(-(sum[1] + b3)));
      o.z = 1.f / (1.f + expf(-(sum[2] + b3)));
      o.w = 1.f / (1.f + expf(-(sum[3] + b3)));
      if (p0 + 3 < P) {
        *(float4*)&out[p0] = o;
      } else {
        if (p0     < P) out[p0]     = o.x;
        if (p0 + 1 < P) out[p0 + 1] = o.y;
        if (p0 + 2 < P) out[p0 + 2] = o.z;
        if (p0 + 3 < P) out[p0 + 3] = o.w;
      }
    }
  }
}

// ---------------------------------------------------------------------------
extern "C" void kernel_launch(void* const* d_in, const int* in_sizes, int n_in,
                              void* d_out, int out_size, void* d_ws, size_t ws_size,
                              hipStream_t stream)
{
  const float* x   = (const float*)d_in[0];
  const int*   ei  = (const int*)d_in[1];
  const int*   ep  = (const int*)d_in[2];
  const float* W1  = (const float*)d_in[3];
  const float* as1 = (const float*)d_in[4];
  const float* ad1 = (const float*)d_in[5];
  const float* b1  = (const float*)d_in[6];
  const float* W2  = (const float*)d_in[7];
  const float* as2 = (const float*)d_in[8];
  const float* ad2 = (const float*)d_in[9];
  const float* b2  = (const float*)d_in[10];
  const float* mw1 = (const float*)d_in[11];
  const float* mb1 = (const float*)d_in[12];
  const float* mw2 = (const float*)d_in[13];
  const float* mb2 = (const float*)d_in[14];
  const float* mw3 = (const float*)d_in[15];
  const float* mb3 = (const float*)d_in[16];

  const int N = in_sizes[0] / 128;
  const int E = in_sizes[1] / 2;
  const int P = in_sizes[2] / 2;
  const int EN = E + N;

  // ---- workspace carve-up (~70 MB) ----
  __bf16* x_bf  = (__bf16*)d_ws;                       // N*128 (later: z_bf)
  __bf16* xw_bf = x_bf  + (size_t)N * 128;             // N*128
  __bf16* h_bf  = xw_bf + (size_t)N * 128;             // N*128
  __bf16* uv_bf = h_bf  + (size_t)N * 128;             // N*256
  __bf16* W1t   = uv_bf + (size_t)N * 256;             // 128*128
  __bf16* W2t   = W1t + 16384;                         // 128*128
  __bf16* mw1t  = W2t + 16384;                         // 256*128
  __bf16* w2t   = mw1t + 32768;                        // 64*128
  float*  as_   = (float*)(w2t + 8192);                // N*4
  float*  ad_   = as_ + (size_t)N * 4;                 // N*4
  int* rowptr   = (int*)(ad_ + (size_t)N * 4);         // N+1
  int* deg      = rowptr + (N + 1);                    // N
  int* cur      = deg + N;                             // N
  int* part     = cur + N;                             // N
  int* bsum     = part + N;                            // 256
  int* csr_src  = bsum + 256;                          // E+N
  __bf16* z_bf  = x_bf;                                // alias (x_bf dead by then)
  float* out    = (float*)d_out;

  const int gEN = (EN + 255) / 256;
  const int nb  = (N + 255) / 256;           // 196 <= 256 (single-block scan2)
  const int gNG = (N + 31) / 32;

  // ---- CSR build (once; both layers share the graph) ----
  hipMemsetAsync(deg, 0, (size_t)2 * N * sizeof(int), stream);  // deg + cur
  hist_kernel <<<gEN, 256, 0, stream>>>(ei, deg, E, N);
  scan1_kernel<<<nb, 256, 0, stream>>>(deg, part, bsum, N);
  scan2_kernel<<<1, 256, 0, stream>>>(bsum, nb);
  scan3_kernel<<<nb, 256, 0, stream>>>(part, bsum, rowptr, N);
  fill_kernel <<<gEN, 256, 0, stream>>>(ei, rowptr, cur, csr_src, E, N);
  convw_kernel<<<128, 256, 0, stream>>>(W1, W2, mw1, mw2, W1t, W2t, mw1t, w2t);
  cvt_bf16_kernel<<<(N * 128 / 4 + 255) / 256, 256, 0, stream>>>(x, x_bf, N * 128);

  // ---- layer 1 (heads=4): x_bf -> xw_bf -> h_bf ----
  nodegemm_kernel<128><<<gNG, 256, 0, stream>>>(x_bf, W1t, xw_bf, N);
  alpha_kernel<4><<<(N + 3) / 4, 256, 0, stream>>>(xw_bf, as1, ad1, as_, ad_, N);
  gat_gather_kernel<4, true><<<(N + 3) / 4, 256, 0, stream>>>(
      csr_src, rowptr, xw_bf, as_, ad_, b1, h_bf, N);

  // ---- layer 2 (heads=1): h_bf -> xw_bf -> z_bf (aliases x_bf) ----
  nodegemm_kernel<128><<<gNG, 256, 0, stream>>>(h_bf, W2t, xw_bf, N);
  alpha_kernel<1><<<(N + 3) / 4, 256, 0, stream>>>(xw_bf, as2, ad2, as_, ad_, N);
  gat_gather_kernel<1, false><<<(N + 3) / 4, 256, 0, stream>>>(
      csr_src, rowptr, xw_bf, as_, ad_, b2, z_bf, N);

  // ---- uv = z @ [mw1_u | mw1_v]  (per-node MLP layer-1 halves) ----
  nodegemm_kernel<256><<<gNG, 256, 0, stream>>>(z_bf, mw1t, uv_bf, N);

  // ---- pair MLP (2-tile, LDS-free, MFMA GEMM2) ----
  pair_kernel<<<(P + 127) / 128, 256, 0, stream>>>(
      uv_bf, ep, mb1, w2t, mb2, mw3, mb3, out, P);
}

// Round 11
// 450.966 us; speedup vs baseline: 7.8834x; 1.0456x over previous
//
#include <hip/hip_runtime.h>
#include <cstdint>
#include <cstddef>

// ---------------------------------------------------------------------------
// GAT link predictor, round 11 (= round-8 design; rounds 9/10 failed compile
// because a trailing backslash in a comment line-continued into the `cur`
// declaration and deleted it. Comment fixed; logic unchanged.)
//  - gat_gather: 8-way predicated edge unroll (8 load chains in flight, no
//    serial tail) -- gathers are L2/L3 latency bound (round-7 profile).
//  - alpha fused into nodegemm epilogue (acc tile already has the data):
//    layer1 = direct per-head store, layer2 = atomicAdd partials.
//  - f32->bf16 cast of x fused into layer-1 nodegemm; mb1 folded into uv.
//  - pair MLP: 2-tile register MFMA (round-7 win), now bias-free.
//  - Softmax max-subtraction skipped (shift-invariant; logits ~N(0,0.25)).
// ---------------------------------------------------------------------------

#define NEG_SLOPE 0.2f

typedef __bf16 bf16x8 __attribute__((ext_vector_type(8)));
typedef float  f32x4  __attribute__((ext_vector_type(4)));

static __device__ __forceinline__ float bflo(unsigned pv) {
  return __uint_as_float(pv << 16);
}
static __device__ __forceinline__ float bfhi(unsigned pv) {
  return __uint_as_float(pv & 0xffff0000u);
}

// --- weight preconvert/transpose to bf16 [NOUT][K] -------------------------
__global__ __launch_bounds__(256) void convw_kernel(
    const float* __restrict__ W1, const float* __restrict__ W2,
    const float* __restrict__ mw1, const float* __restrict__ mw2,
    __bf16* __restrict__ W1t, __bf16* __restrict__ W2t,
    __bf16* __restrict__ mw1t, __bf16* __restrict__ w2t)
{
  const int i = blockIdx.x * 256 + threadIdx.x;
  if (i < 16384) {
    const int nn = i >> 7, k = i & 127;
    W1t[i] = (__bf16)W1[k * 128 + nn];
    W2t[i] = (__bf16)W2[k * 128 + nn];
  }
  if (i < 32768) {
    const int j = i >> 7, k = i & 127;
    mw1t[i] = (__bf16)((j < 128) ? mw1[k * 128 + j]
                                 : mw1[(128 + k) * 128 + (j - 128)]);
  }
  if (i < 8192) {
    const int nn = i >> 7, k = i & 127;
    w2t[i] = (__bf16)mw2[k * 64 + nn];
  }
}

// --- node GEMM on MFMA: C[n][NOUT] = A[n][128] @ Wt^T ----------------------
// Optional fused epilogues:
//   HEADS=4: as/ad per-head direct store (wave == head)
//   HEADS=1: as/ad partial atomicAdd (as_out/ad_out pre-zeroed)
//   FOLDB:   add vbias[col-128] to cols >= 128 (mb1 fold for uv)
//   AF32:    A is fp32, cast to bf16 at load (x input)
template<int NOUT, int HEADS, bool AF32, bool FOLDB>
__global__ __launch_bounds__(256) void nodegemm_kernel(
    const __bf16* __restrict__ A, const float* __restrict__ A32,
    const __bf16* __restrict__ Wt, __bf16* __restrict__ C,
    const float* __restrict__ asrc, const float* __restrict__ adst,
    float* __restrict__ as_out, float* __restrict__ ad_out,
    const float* __restrict__ vbias, int n)
{
  constexpr int NT = NOUT / 64;
  const int tid = threadIdx.x;
  const int wave = tid >> 6, lane = tid & 63;
  const int l16 = lane & 15;
  const int kl  = (lane >> 4) << 3;
  const int r4  = (lane >> 4) << 2;
  const int n0  = wave * (NOUT / 4);
  const int rowbase = blockIdx.x * 32;

  bf16x8 a[2][4];
  #pragma unroll
  for (int mt = 0; mt < 2; ++mt) {
    int row = rowbase + mt * 16 + l16;
    if (row >= n) row = n - 1;
    const size_t rb = (size_t)row * 128;
    #pragma unroll
    for (int ks = 0; ks < 4; ++ks) {
      if (AF32) {
        const float4 f0 = *(const float4*)&A32[rb + ks * 32 + kl];
        const float4 f1 = *(const float4*)&A32[rb + ks * 32 + kl + 4];
        bf16x8 t;
        t[0] = (__bf16)f0.x; t[1] = (__bf16)f0.y;
        t[2] = (__bf16)f0.z; t[3] = (__bf16)f0.w;
        t[4] = (__bf16)f1.x; t[5] = (__bf16)f1.y;
        t[6] = (__bf16)f1.z; t[7] = (__bf16)f1.w;
        a[mt][ks] = t;
      } else {
        a[mt][ks] = *(const bf16x8*)&A[rb + ks * 32 + kl];
      }
    }
  }
  f32x4 acc[2][NT];
  #pragma unroll
  for (int mt = 0; mt < 2; ++mt)
    #pragma unroll
    for (int nt = 0; nt < NT; ++nt) acc[mt][nt] = (f32x4){0.f, 0.f, 0.f, 0.f};

  #pragma unroll
  for (int ks = 0; ks < 4; ++ks) {
    #pragma unroll
    for (int nt = 0; nt < NT; ++nt) {
      const bf16x8 b =
          *(const bf16x8*)&Wt[(size_t)(n0 + nt * 16 + l16) * 128 + ks * 32 + kl];
      #pragma unroll
      for (int mt = 0; mt < 2; ++mt)
        acc[mt][nt] = __builtin_amdgcn_mfma_f32_16x16x32_bf16(
            a[mt][ks], b, acc[mt][nt], 0, 0, 0);
    }
  }

  // D layout: col = lane&15 (per 16-tile), row = (lane>>4)*4 + j   (m89)
  #pragma unroll
  for (int mt = 0; mt < 2; ++mt) {
    #pragma unroll
    for (int nt = 0; nt < NT; ++nt) {
      const int col = n0 + nt * 16 + l16;
      float vb = 0.f;
      if (FOLDB) vb = (col >= 128) ? vbias[col - 128] : 0.f;
      #pragma unroll
      for (int j = 0; j < 4; ++j) {
        const int row = rowbase + mt * 16 + r4 + j;
        if (row < n) C[(size_t)row * NOUT + col] = (__bf16)(acc[mt][nt][j] + vb);
      }
    }
  }

  // fused alpha epilogue
  if (HEADS > 0) {
    float a_s[NT], a_d[NT];
    #pragma unroll
    for (int nt = 0; nt < NT; ++nt) {
      const int col = n0 + nt * 16 + l16;
      a_s[nt] = asrc[col]; a_d[nt] = adst[col];
    }
    #pragma unroll
    for (int mt = 0; mt < 2; ++mt) {
      #pragma unroll
      for (int j = 0; j < 4; ++j) {
        float ps = 0.f, pd = 0.f;
        #pragma unroll
        for (int nt = 0; nt < NT; ++nt) {
          ps += acc[mt][nt][j] * a_s[nt];
          pd += acc[mt][nt][j] * a_d[nt];
        }
        #pragma unroll
        for (int m = 1; m <= 8; m <<= 1) {   // reduce the 16-lane col group
          ps += __shfl_xor(ps, m); pd += __shfl_xor(pd, m);
        }
        const int row = rowbase + mt * 16 + r4 + j;
        if (l16 == 0 && row < n) {           // row<n also kills clamped dups
          if (HEADS == 4) {                  // wave's 32 cols == head `wave`
            as_out[row * 4 + wave] = ps;
            ad_out[row * 4 + wave] = pd;
          } else {                           // partial over 32 of 128 cols
            atomicAdd(&as_out[row], ps);
            atomicAdd(&ad_out[row], pd);
          }
        }
      }
    }
  }
}

// --- CSR build: histogram -> block scan -> scatter -------------------------
__global__ __launch_bounds__(256) void hist_kernel(
    const int* __restrict__ ei, int* __restrict__ deg, int E, int n)
{
  const int e = blockIdx.x * 256 + threadIdx.x;
  if (e >= E + n) return;
  const int d = (e < E) ? ei[E + e] : e - E;   // self-loops appended
  atomicAdd(&deg[d], 1);
}

__global__ __launch_bounds__(256) void scan1_kernel(
    const int* __restrict__ deg, int* __restrict__ part,
    int* __restrict__ bsum, int n)
{
  __shared__ int s[256];
  const int i = blockIdx.x * 256 + threadIdx.x;
  s[threadIdx.x] = (i < n) ? deg[i] : 0;
  __syncthreads();
  #pragma unroll
  for (int off = 1; off < 256; off <<= 1) {
    const int t = (threadIdx.x >= off) ? s[threadIdx.x - off] : 0;
    __syncthreads();
    s[threadIdx.x] += t;
    __syncthreads();
  }
  if (i < n) part[i] = s[threadIdx.x];
  if (threadIdx.x == 255) bsum[blockIdx.x] = s[255];
}

__global__ __launch_bounds__(256) void scan2_kernel(int* __restrict__ bsum, int nb)
{
  __shared__ int s[256];
  s[threadIdx.x] = (threadIdx.x < nb) ? bsum[threadIdx.x] : 0;
  __syncthreads();
  #pragma unroll
  for (int off = 1; off < 256; off <<= 1) {
    const int t = (threadIdx.x >= off) ? s[threadIdx.x - off] : 0;
    __syncthreads();
    s[threadIdx.x] += t;
    __syncthreads();
  }
  const int excl = (threadIdx.x == 0) ? 0 : s[threadIdx.x - 1];
  if (threadIdx.x < nb) bsum[threadIdx.x] = excl;
}

__global__ __launch_bounds__(256) void scan3_kernel(
    const int* __restrict__ part, const int* __restrict__ bsum,
    int* __restrict__ rowptr, int n)
{
  const int i = blockIdx.x * 256 + threadIdx.x;
  if (i < n) rowptr[i + 1] = part[i] + bsum[blockIdx.x];
  if (i == 0) rowptr[0] = 0;
}

__global__ __launch_bounds__(256) void fill_kernel(
    const int* __restrict__ ei, const int* __restrict__ rowptr,
    int* __restrict__ cur, int* __restrict__ csr_src, int E, int n)
{
  const int e = blockIdx.x * 256 + threadIdx.x;
  if (e >= E + n) return;
  int s, d;
  if (e < E) { s = ei[e]; d = ei[E + e]; }
  else       { s = e - E; d = s; }
  const int pos = rowptr[d] + atomicAdd(&cur[d], 1);
  csr_src[pos] = s;
}

// --- fused GAT aggregate: one wave per dst, 8-way predicated unroll --------
template<int HEADS, bool DO_ELU>
__global__ __launch_bounds__(256) void gat_gather_kernel(
    const int* __restrict__ csr_src, const int* __restrict__ rowptr,
    const __bf16* __restrict__ xw,
    const float* __restrict__ as_, const float* __restrict__ ad_,
    const float* __restrict__ bias,
    __bf16* __restrict__ out, int n)
{
  const int d = blockIdx.x * 4 + (threadIdx.x >> 6);
  if (d >= n) return;
  const int lane = threadIdx.x & 63;
  const int c0 = lane * 2;
  constexpr int C = 128 / HEADS;
  const int head = c0 / C;
  const float ad_d = ad_[d * HEADS + head];
  const int r0 = rowptr[d], r1 = rowptr[d + 1];
  float accx = 0.f, accy = 0.f, den = 0.f;

  for (int i = r0; i < r1; i += 8) {
    int s[8];
    #pragma unroll
    for (int u = 0; u < 8; ++u)
      s[u] = csr_src[(i + u < r1) ? i + u : r1 - 1];
    float lg[8]; unsigned pv[8];
    #pragma unroll
    for (int u = 0; u < 8; ++u) {          // 16 independent loads in flight
      lg[u] = as_[s[u] * HEADS + head];
      pv[u] = *(const unsigned*)&xw[(size_t)s[u] * 128 + c0];
    }
    #pragma unroll
    for (int u = 0; u < 8; ++u) {
      float l = lg[u] + ad_d;
      l = (l > 0.f) ? l : NEG_SLOPE * l;
      const float ex = (i + u < r1) ? __expf(l) : 0.f;
      accx += ex * bflo(pv[u]); accy += ex * bfhi(pv[u]); den += ex;
    }
  }

  const float inv = 1.f / den;              // deg >= 1 (self-loop) -> no /0
  float rx = accx * inv + bias[c0];
  float ry = accy * inv + bias[c0 + 1];
  if (DO_ELU) {
    rx = rx > 0.f ? rx : expm1f(rx);
    ry = ry > 0.f ? ry : expm1f(ry);
  }
  union { __bf16 b[2]; unsigned u; } pk;
  pk.b[0] = (__bf16)rx; pk.b[1] = (__bf16)ry;
  *(unsigned*)&out[(size_t)d * 128 + c0] = pk.u;
}

// --- pair MLP: 2 m-tiles/wave (32 pairs), 128 pairs/block ------------------
// h1 = relu(uv[i,:128] + uv'[j,128:])  (mb1 pre-folded into uv v-half)
// -> MFMA GEMM2 (B-frag shared across tiles) -> dot64 -> sigmoid.
__global__ __launch_bounds__(256) void pair_kernel(
    const __bf16* __restrict__ uv, const int* __restrict__ pairs,
    const __bf16* __restrict__ w2t, const float* __restrict__ mb2,
    const float* __restrict__ mw3, const float* __restrict__ mb3,
    float* __restrict__ out, int P)
{
  const int tid = threadIdx.x;
  const int wave = tid >> 6, lane = tid & 63;
  const int l16 = lane & 15;
  const int kl  = (lane >> 4) << 3;
  const int r4  = (lane >> 4) << 2;
  const int mbase = blockIdx.x * 128 + wave * 32;

  size_t ib[2], jb[2];
  #pragma unroll
  for (int t = 0; t < 2; ++t) {
    int p = mbase + t * 16 + l16;
    if (p >= P) p = P - 1;
    ib[t] = (size_t)pairs[p] * 256;
    jb[t] = (size_t)pairs[P + p] * 256 + 128;
  }

  bf16x8 a[2][4];
  #pragma unroll
  for (int t = 0; t < 2; ++t) {
    bf16x8 uu[4], vv[4];
    #pragma unroll
    for (int s = 0; s < 4; ++s) {
      uu[s] = *(const bf16x8*)&uv[ib[t] + s * 32 + kl];
      vv[s] = *(const bf16x8*)&uv[jb[t] + s * 32 + kl];
    }
    #pragma unroll
    for (int s = 0; s < 4; ++s) {
      #pragma unroll
      for (int e = 0; e < 8; ++e)
        a[t][s][e] = (__bf16)fmaxf((float)uu[s][e] + (float)vv[s][e], 0.f);
    }
  }

  f32x4 acc[2][4] = {};
  #pragma unroll
  for (int ks = 0; ks < 4; ++ks) {
    #pragma unroll
    for (int ni = 0; ni < 4; ++ni) {
      const bf16x8 b = *(const bf16x8*)&w2t[(size_t)(ni * 16 + l16) * 128 + ks * 32 + kl];
      #pragma unroll
      for (int t = 0; t < 2; ++t)
        acc[t][ni] = __builtin_amdgcn_mfma_f32_16x16x32_bf16(
            a[t][ks], b, acc[t][ni], 0, 0, 0);
    }
  }

  #pragma unroll
  for (int t = 0; t < 2; ++t) {
    float sum[4] = {0.f, 0.f, 0.f, 0.f};
    #pragma unroll
    for (int ni = 0; ni < 4; ++ni) {
      const int col = ni * 16 + l16;
      const float b2 = mb2[col];
      const float w3 = mw3[col];
      #pragma unroll
      for (int j = 0; j < 4; ++j)
        sum[j] += fmaxf(acc[t][ni][j] + b2, 0.f) * w3;
    }
    #pragma unroll
    for (int m = 1; m <= 8; m <<= 1) {
      #pragma unroll
      for (int j = 0; j < 4; ++j) sum[j] += __shfl_xor(sum[j], m);
    }
    if (l16 == 0) {
      const int p0 = mbase + t * 16 + r4;
      const float b3 = mb3[0];
      float4 o;
      o.x = 1.f / (1.f + __expf(-(sum[0] + b3)));
      o.y = 1.f / (1.f + __expf(-(sum[1] + b3)));
      o.z = 1.f / (1.f + __expf(-(sum[2] + b3)));
      o.w = 1.f / (1.f + __expf(-(sum[3] + b3)));
      if (p0 + 3 < P) {
        *(float4*)&out[p0] = o;
      } else {
        if (p0     < P) out[p0]     = o.x;
        if (p0 + 1 < P) out[p0 + 1] = o.y;
        if (p0 + 2 < P) out[p0 + 2] = o.z;
        if (p0 + 3 < P) out[p0 + 3] = o.w;
      }
    }
  }
}

// ---------------------------------------------------------------------------
extern "C" void kernel_launch(void* const* d_in, const int* in_sizes, int n_in,
                              void* d_out, int out_size, void* d_ws, size_t ws_size,
                              hipStream_t stream)
{
  const float* x   = (const float*)d_in[0];
  const int*   ei  = (const int*)d_in[1];
  const int*   ep  = (const int*)d_in[2];
  const float* W1  = (const float*)d_in[3];
  const float* as1 = (const float*)d_in[4];
  const float* ad1 = (const float*)d_in[5];
  const float* b1  = (const float*)d_in[6];
  const float* W2  = (const float*)d_in[7];
  const float* as2 = (const float*)d_in[8];
  const float* ad2 = (const float*)d_in[9];
  const float* b2  = (const float*)d_in[10];
  const float* mw1 = (const float*)d_in[11];
  const float* mb1 = (const float*)d_in[12];
  const float* mw2 = (const float*)d_in[13];
  const float* mb2 = (const float*)d_in[14];
  const float* mw3 = (const float*)d_in[15];
  const float* mb3 = (const float*)d_in[16];

  const int N = in_sizes[0] / 128;
  const int E = in_sizes[1] / 2;
  const int P = in_sizes[2] / 2;
  const int EN = E + N;

  // ---- workspace carve-up (~70 MB) ----
  __bf16* z_bf  = (__bf16*)d_ws;                       // N*128
  __bf16* xw_bf = z_bf  + (size_t)N * 128;             // N*128
  __bf16* h_bf  = xw_bf + (size_t)N * 128;             // N*128
  __bf16* uv_bf = h_bf  + (size_t)N * 128;             // N*256
  __bf16* W1t   = uv_bf + (size_t)N * 256;             // 128*128
  __bf16* W2t   = W1t + 16384;                         // 128*128
  __bf16* mw1t  = W2t + 16384;                         // 256*128
  __bf16* w2t   = mw1t + 32768;                        // 64*128
  float*  as_   = (float*)(w2t + 8192);                // N*4 (layer1, stored)
  float*  ad_   = as_ + (size_t)N * 4;                 // N*4
  int*    deg   = (int*)(ad_ + (size_t)N * 4);         // N (zeroed region start)
  int*    cur   = deg + N;                             // N (zeroed)
  float*  as2v  = (float*)(cur + N);                   // N (zeroed)
  float*  ad2v  = as2v + N;                            // N (zeroed region end)
  int* part     = (int*)(ad2v + N);                    // N
  int* bsum     = part + N;                            // 256
  int* rowptr   = bsum + 256;                          // N+1
  int* csr_src  = rowptr + (N + 1);                    // E+N
  float* out    = (float*)d_out;

  const int gEN = (EN + 255) / 256;
  const int nb  = (N + 255) / 256;           // 196 <= 256 (single-block scan2)
  const int gNG = (N + 31) / 32;

  // ---- CSR build (once; both layers share the graph) + zero accumulators --
  (void)hipMemsetAsync(deg, 0, (size_t)4 * N * sizeof(int), stream);  // deg,cur,as2v,ad2v
  hist_kernel <<<gEN, 256, 0, stream>>>(ei, deg, E, N);
  scan1_kernel<<<nb, 256, 0, stream>>>(deg, part, bsum, N);
  scan2_kernel<<<1, 256, 0, stream>>>(bsum, nb);
  scan3_kernel<<<nb, 256, 0, stream>>>(part, bsum, rowptr, N);
  fill_kernel <<<gEN, 256, 0, stream>>>(ei, rowptr, cur, csr_src, E, N);
  convw_kernel<<<128, 256, 0, stream>>>(W1, W2, mw1, mw2, W1t, W2t, mw1t, w2t);

  // ---- layer 1 (heads=4): x -> xw_bf (+as_/ad_ fused) -> h_bf ----
  nodegemm_kernel<128, 4, true, false><<<gNG, 256, 0, stream>>>(
      nullptr, x, W1t, xw_bf, as1, ad1, as_, ad_, nullptr, N);
  gat_gather_kernel<4, true><<<(N + 3) / 4, 256, 0, stream>>>(
      csr_src, rowptr, xw_bf, as_, ad_, b1, h_bf, N);

  // ---- layer 2 (heads=1): h_bf -> xw_bf (+as2v/ad2v fused) -> z_bf ----
  nodegemm_kernel<128, 1, false, false><<<gNG, 256, 0, stream>>>(
      h_bf, nullptr, W2t, xw_bf, as2, ad2, as2v, ad2v, nullptr, N);
  gat_gather_kernel<1, false><<<(N + 3) / 4, 256, 0, stream>>>(
      csr_src, rowptr, xw_bf, as2v, ad2v, b2, z_bf, N);

  // ---- uv = z @ [mw1_u | mw1_v] with mb1 folded into v-half ----
  nodegemm_kernel<256, 0, false, true><<<gNG, 256, 0, stream>>>(
      z_bf, nullptr, mw1t, uv_bf, nullptr, nullptr, nullptr, nullptr, mb1, N);

  // ---- pair MLP (2-tile, LDS-free, MFMA GEMM2) ----
  pair_kernel<<<(P + 127) / 128, 256, 0, stream>>>(
      uv_bf, ep, w2t, mb2, mw3, mb3, out, P);
}

// Round 12
// 450.713 us; speedup vs baseline: 7.8878x; 1.0006x over previous
//
#include <hip/hip_runtime.h>
#include <hip/hip_fp8.h>
#include <cstdint>
#include <cstddef>

// ---------------------------------------------------------------------------
// GAT link predictor, round 12.
//  - Round-11 diagnosis: gathers + pair are random-row L2-miss/fabric
//    THROUGHPUT bound (latency floor ~5us vs ~95us observed; pair moves
//    410MB logical at 4TB/s). Lever: bytes/row.
//  - This round: fp8 e4m3 (OCP, gfx950-native) STORAGE for all randomly
//    gathered buffers: xw (both layers) and uv. Compute stays bf16/fp32;
//    quantize in nodegemm epilogue, dequantize in registers at the gather.
//  - Everything else = round-11 (fused alpha, 8-way unroll, 2-tile pair).
//  - NOTE: no comment in this file may end with a backslash (rounds 9/10
//    died to a line-continuation eating the next declaration).
// ---------------------------------------------------------------------------

#define NEG_SLOPE 0.2f

typedef __bf16 bf16x8 __attribute__((ext_vector_type(8)));
typedef float  f32x4  __attribute__((ext_vector_type(4)));

static __device__ __forceinline__ float fp8_to_f32(unsigned b) {
  __hip_fp8_e4m3 t; t.__x = (__hip_fp8_storage_t)(b & 0xff);
  return (float)t;
}
static __device__ __forceinline__ unsigned char f32_to_fp8(float f) {
  __hip_fp8_e4m3 t(f); return (unsigned char)t.__x;
}
static __device__ __forceinline__ void fp8x4_to_f32(unsigned w, float* o) {
  o[0] = fp8_to_f32(w);
  o[1] = fp8_to_f32(w >> 8);
  o[2] = fp8_to_f32(w >> 16);
  o[3] = fp8_to_f32(w >> 24);
}

// --- weight preconvert/transpose to bf16 [NOUT][K] -------------------------
__global__ __launch_bounds__(256) void convw_kernel(
    const float* __restrict__ W1, const float* __restrict__ W2,
    const float* __restrict__ mw1, const float* __restrict__ mw2,
    __bf16* __restrict__ W1t, __bf16* __restrict__ W2t,
    __bf16* __restrict__ mw1t, __bf16* __restrict__ w2t)
{
  const int i = blockIdx.x * 256 + threadIdx.x;
  if (i < 16384) {
    const int nn = i >> 7, k = i & 127;
    W1t[i] = (__bf16)W1[k * 128 + nn];
    W2t[i] = (__bf16)W2[k * 128 + nn];
  }
  if (i < 32768) {
    const int j = i >> 7, k = i & 127;
    mw1t[i] = (__bf16)((j < 128) ? mw1[k * 128 + j]
                                 : mw1[(128 + k) * 128 + (j - 128)]);
  }
  if (i < 8192) {
    const int nn = i >> 7, k = i & 127;
    w2t[i] = (__bf16)mw2[k * 64 + nn];
  }
}

// --- node GEMM on MFMA: C8[n][NOUT] = fp8(A[n][128] @ Wt^T + fold) ---------
// Epilogues: HEADS=4 per-head alpha store; HEADS=1 alpha atomicAdd;
// FOLDB adds vbias to cols>=128; AF32 reads fp32 A.
template<int NOUT, int HEADS, bool AF32, bool FOLDB>
__global__ __launch_bounds__(256) void nodegemm_kernel(
    const __bf16* __restrict__ A, const float* __restrict__ A32,
    const __bf16* __restrict__ Wt, unsigned char* __restrict__ C8,
    const float* __restrict__ asrc, const float* __restrict__ adst,
    float* __restrict__ as_out, float* __restrict__ ad_out,
    const float* __restrict__ vbias, int n)
{
  constexpr int NT = NOUT / 64;
  const int tid = threadIdx.x;
  const int wave = tid >> 6, lane = tid & 63;
  const int l16 = lane & 15;
  const int kl  = (lane >> 4) << 3;
  const int r4  = (lane >> 4) << 2;
  const int n0  = wave * (NOUT / 4);
  const int rowbase = blockIdx.x * 32;

  bf16x8 a[2][4];
  #pragma unroll
  for (int mt = 0; mt < 2; ++mt) {
    int row = rowbase + mt * 16 + l16;
    if (row >= n) row = n - 1;
    const size_t rb = (size_t)row * 128;
    #pragma unroll
    for (int ks = 0; ks < 4; ++ks) {
      if (AF32) {
        const float4 f0 = *(const float4*)&A32[rb + ks * 32 + kl];
        const float4 f1 = *(const float4*)&A32[rb + ks * 32 + kl + 4];
        bf16x8 t;
        t[0] = (__bf16)f0.x; t[1] = (__bf16)f0.y;
        t[2] = (__bf16)f0.z; t[3] = (__bf16)f0.w;
        t[4] = (__bf16)f1.x; t[5] = (__bf16)f1.y;
        t[6] = (__bf16)f1.z; t[7] = (__bf16)f1.w;
        a[mt][ks] = t;
      } else {
        a[mt][ks] = *(const bf16x8*)&A[rb + ks * 32 + kl];
      }
    }
  }
  f32x4 acc[2][NT];
  #pragma unroll
  for (int mt = 0; mt < 2; ++mt)
    #pragma unroll
    for (int nt = 0; nt < NT; ++nt) acc[mt][nt] = (f32x4){0.f, 0.f, 0.f, 0.f};

  #pragma unroll
  for (int ks = 0; ks < 4; ++ks) {
    #pragma unroll
    for (int nt = 0; nt < NT; ++nt) {
      const bf16x8 b =
          *(const bf16x8*)&Wt[(size_t)(n0 + nt * 16 + l16) * 128 + ks * 32 + kl];
      #pragma unroll
      for (int mt = 0; mt < 2; ++mt)
        acc[mt][nt] = __builtin_amdgcn_mfma_f32_16x16x32_bf16(
            a[mt][ks], b, acc[mt][nt], 0, 0, 0);
    }
  }

  // D layout: col = lane&15 (per 16-tile), row = (lane>>4)*4 + j   (m89)
  #pragma unroll
  for (int mt = 0; mt < 2; ++mt) {
    #pragma unroll
    for (int nt = 0; nt < NT; ++nt) {
      const int col = n0 + nt * 16 + l16;
      float vb = 0.f;
      if (FOLDB) vb = (col >= 128) ? vbias[col - 128] : 0.f;
      #pragma unroll
      for (int j = 0; j < 4; ++j) {
        const int row = rowbase + mt * 16 + r4 + j;
        if (row < n) C8[(size_t)row * NOUT + col] = f32_to_fp8(acc[mt][nt][j] + vb);
      }
    }
  }

  // fused alpha epilogue (from fp32 acc, pre-quantization)
  if (HEADS > 0) {
    float a_s[NT], a_d[NT];
    #pragma unroll
    for (int nt = 0; nt < NT; ++nt) {
      const int col = n0 + nt * 16 + l16;
      a_s[nt] = asrc[col]; a_d[nt] = adst[col];
    }
    #pragma unroll
    for (int mt = 0; mt < 2; ++mt) {
      #pragma unroll
      for (int j = 0; j < 4; ++j) {
        float ps = 0.f, pd = 0.f;
        #pragma unroll
        for (int nt = 0; nt < NT; ++nt) {
          ps += acc[mt][nt][j] * a_s[nt];
          pd += acc[mt][nt][j] * a_d[nt];
        }
        #pragma unroll
        for (int m = 1; m <= 8; m <<= 1) {   // reduce the 16-lane col group
          ps += __shfl_xor(ps, m); pd += __shfl_xor(pd, m);
        }
        const int row = rowbase + mt * 16 + r4 + j;
        if (l16 == 0 && row < n) {           // row<n also kills clamped dups
          if (HEADS == 4) {                  // wave's 32 cols == head `wave`
            as_out[row * 4 + wave] = ps;
            ad_out[row * 4 + wave] = pd;
          } else {                           // partial over 32 of 128 cols
            atomicAdd(&as_out[row], ps);
            atomicAdd(&ad_out[row], pd);
          }
        }
      }
    }
  }
}

// --- CSR build: histogram -> block scan -> scatter -------------------------
__global__ __launch_bounds__(256) void hist_kernel(
    const int* __restrict__ ei, int* __restrict__ deg, int E, int n)
{
  const int e = blockIdx.x * 256 + threadIdx.x;
  if (e >= E + n) return;
  const int d = (e < E) ? ei[E + e] : e - E;   // self-loops appended
  atomicAdd(&deg[d], 1);
}

__global__ __launch_bounds__(256) void scan1_kernel(
    const int* __restrict__ deg, int* __restrict__ part,
    int* __restrict__ bsum, int n)
{
  __shared__ int s[256];
  const int i = blockIdx.x * 256 + threadIdx.x;
  s[threadIdx.x] = (i < n) ? deg[i] : 0;
  __syncthreads();
  #pragma unroll
  for (int off = 1; off < 256; off <<= 1) {
    const int t = (threadIdx.x >= off) ? s[threadIdx.x - off] : 0;
    __syncthreads();
    s[threadIdx.x] += t;
    __syncthreads();
  }
  if (i < n) part[i] = s[threadIdx.x];
  if (threadIdx.x == 255) bsum[blockIdx.x] = s[255];
}

__global__ __launch_bounds__(256) void scan2_kernel(int* __restrict__ bsum, int nb)
{
  __shared__ int s[256];
  s[threadIdx.x] = (threadIdx.x < nb) ? bsum[threadIdx.x] : 0;
  __syncthreads();
  #pragma unroll
  for (int off = 1; off < 256; off <<= 1) {
    const int t = (threadIdx.x >= off) ? s[threadIdx.x - off] : 0;
    __syncthreads();
    s[threadIdx.x] += t;
    __syncthreads();
  }
  const int excl = (threadIdx.x == 0) ? 0 : s[threadIdx.x - 1];
  if (threadIdx.x < nb) bsum[threadIdx.x] = excl;
}

__global__ __launch_bounds__(256) void scan3_kernel(
    const int* __restrict__ part, const int* __restrict__ bsum,
    int* __restrict__ rowptr, int n)
{
  const int i = blockIdx.x * 256 + threadIdx.x;
  if (i < n) rowptr[i + 1] = part[i] + bsum[blockIdx.x];
  if (i == 0) rowptr[0] = 0;
}

__global__ __launch_bounds__(256) void fill_kernel(
    const int* __restrict__ ei, const int* __restrict__ rowptr,
    int* __restrict__ cur, int* __restrict__ csr_src, int E, int n)
{
  const int e = blockIdx.x * 256 + threadIdx.x;
  if (e >= E + n) return;
  int s, d;
  if (e < E) { s = ei[e]; d = ei[E + e]; }
  else       { s = e - E; d = s; }
  const int pos = rowptr[d] + atomicAdd(&cur[d], 1);
  csr_src[pos] = s;
}

// --- fused GAT aggregate: one wave per dst, 8-way unroll, fp8 rows ---------
template<int HEADS, bool DO_ELU>
__global__ __launch_bounds__(256) void gat_gather_kernel(
    const int* __restrict__ csr_src, const int* __restrict__ rowptr,
    const unsigned char* __restrict__ xw8,
    const float* __restrict__ as_, const float* __restrict__ ad_,
    const float* __restrict__ bias,
    __bf16* __restrict__ out, int n)
{
  const int d = blockIdx.x * 4 + (threadIdx.x >> 6);
  if (d >= n) return;
  const int lane = threadIdx.x & 63;
  const int c0 = lane * 2;
  constexpr int C = 128 / HEADS;
  const int head = c0 / C;
  const float ad_d = ad_[d * HEADS + head];
  const int r0 = rowptr[d], r1 = rowptr[d + 1];
  float accx = 0.f, accy = 0.f, den = 0.f;

  for (int i = r0; i < r1; i += 8) {
    int s[8];
    #pragma unroll
    for (int u = 0; u < 8; ++u)
      s[u] = csr_src[(i + u < r1) ? i + u : r1 - 1];
    float lg[8]; unsigned short pv[8];
    #pragma unroll
    for (int u = 0; u < 8; ++u) {          // 16 independent loads in flight
      lg[u] = as_[s[u] * HEADS + head];
      pv[u] = *(const unsigned short*)&xw8[(size_t)s[u] * 128 + c0];
    }
    #pragma unroll
    for (int u = 0; u < 8; ++u) {
      float l = lg[u] + ad_d;
      l = (l > 0.f) ? l : NEG_SLOPE * l;
      const float ex = (i + u < r1) ? __expf(l) : 0.f;
      accx += ex * fp8_to_f32(pv[u]);
      accy += ex * fp8_to_f32((unsigned)pv[u] >> 8);
      den  += ex;
    }
  }

  const float inv = 1.f / den;              // deg >= 1 (self-loop) -> no /0
  float rx = accx * inv + bias[c0];
  float ry = accy * inv + bias[c0 + 1];
  if (DO_ELU) {
    rx = rx > 0.f ? rx : expm1f(rx);
    ry = ry > 0.f ? ry : expm1f(ry);
  }
  union { __bf16 b[2]; unsigned u; } pk;
  pk.b[0] = (__bf16)rx; pk.b[1] = (__bf16)ry;
  *(unsigned*)&out[(size_t)d * 128 + c0] = pk.u;
}

// --- pair MLP: 2 m-tiles/wave, fp8 uv rows ---------------------------------
// h1 = relu(uv[i,:128] + uv[j,128:]) (mb1 pre-folded into v-half) in regs
// -> MFMA GEMM2 bf16 (B-frag shared across tiles) -> dot64 -> sigmoid.
__global__ __launch_bounds__(256) void pair_kernel(
    const unsigned char* __restrict__ uv8, const int* __restrict__ pairs,
    const __bf16* __restrict__ w2t, const float* __restrict__ mb2,
    const float* __restrict__ mw3, const float* __restrict__ mb3,
    float* __restrict__ out, int P)
{
  const int tid = threadIdx.x;
  const int wave = tid >> 6, lane = tid & 63;
  const int l16 = lane & 15;
  const int kl  = (lane >> 4) << 3;
  const int r4  = (lane >> 4) << 2;
  const int mbase = blockIdx.x * 128 + wave * 32;

  size_t ib[2], jb[2];
  #pragma unroll
  for (int t = 0; t < 2; ++t) {
    int p = mbase + t * 16 + l16;
    if (p >= P) p = P - 1;
    ib[t] = (size_t)pairs[p] * 256;
    jb[t] = (size_t)pairs[P + p] * 256 + 128;
  }

  bf16x8 a[2][4];
  #pragma unroll
  for (int t = 0; t < 2; ++t) {
    uint2 du[4], dv[4];
    #pragma unroll
    for (int s = 0; s < 4; ++s) {          // 16 independent 8B loads in flight
      du[s] = *(const uint2*)&uv8[ib[t] + s * 32 + kl];
      dv[s] = *(const uint2*)&uv8[jb[t] + s * 32 + kl];
    }
    #pragma unroll
    for (int s = 0; s < 4; ++s) {
      float fu[8], fv[8];
      fp8x4_to_f32(du[s].x, fu); fp8x4_to_f32(du[s].y, fu + 4);
      fp8x4_to_f32(dv[s].x, fv); fp8x4_to_f32(dv[s].y, fv + 4);
      #pragma unroll
      for (int e = 0; e < 8; ++e)
        a[t][s][e] = (__bf16)fmaxf(fu[e] + fv[e], 0.f);
    }
  }

  f32x4 acc[2][4] = {};
  #pragma unroll
  for (int ks = 0; ks < 4; ++ks) {
    #pragma unroll
    for (int ni = 0; ni < 4; ++ni) {
      const bf16x8 b = *(const bf16x8*)&w2t[(size_t)(ni * 16 + l16) * 128 + ks * 32 + kl];
      #pragma unroll
      for (int t = 0; t < 2; ++t)
        acc[t][ni] = __builtin_amdgcn_mfma_f32_16x16x32_bf16(
            a[t][ks], b, acc[t][ni], 0, 0, 0);
    }
  }

  #pragma unroll
  for (int t = 0; t < 2; ++t) {
    float sum[4] = {0.f, 0.f, 0.f, 0.f};
    #pragma unroll
    for (int ni = 0; ni < 4; ++ni) {
      const int col = ni * 16 + l16;
      const float b2 = mb2[col];
      const float w3 = mw3[col];
      #pragma unroll
      for (int j = 0; j < 4; ++j)
        sum[j] += fmaxf(acc[t][ni][j] + b2, 0.f) * w3;
    }
    #pragma unroll
    for (int m = 1; m <= 8; m <<= 1) {
      #pragma unroll
      for (int j = 0; j < 4; ++j) sum[j] += __shfl_xor(sum[j], m);
    }
    if (l16 == 0) {
      const int p0 = mbase + t * 16 + r4;
      const float b3 = mb3[0];
      float4 o;
      o.x = 1.f / (1.f + __expf(-(sum[0] + b3)));
      o.y = 1.f / (1.f + __expf(-(sum[1] + b3)));
      o.z = 1.f / (1.f + __expf(-(sum[2] + b3)));
      o.w = 1.f / (1.f + __expf(-(sum[3] + b3)));
      if (p0 + 3 < P) {
        *(float4*)&out[p0] = o;
      } else {
        if (p0     < P) out[p0]     = o.x;
        if (p0 + 1 < P) out[p0 + 1] = o.y;
        if (p0 + 2 < P) out[p0 + 2] = o.z;
        if (p0 + 3 < P) out[p0 + 3] = o.w;
      }
    }
  }
}

// ---------------------------------------------------------------------------
extern "C" void kernel_launch(void* const* d_in, const int* in_sizes, int n_in,
                              void* d_out, int out_size, void* d_ws, size_t ws_size,
                              hipStream_t stream)
{
  const float* x   = (const float*)d_in[0];
  const int*   ei  = (const int*)d_in[1];
  const int*   ep  = (const int*)d_in[2];
  const float* W1  = (const float*)d_in[3];
  const float* as1 = (const float*)d_in[4];
  const float* ad1 = (const float*)d_in[5];
  const float* b1  = (const float*)d_in[6];
  const float* W2  = (const float*)d_in[7];
  const float* as2 = (const float*)d_in[8];
  const float* ad2 = (const float*)d_in[9];
  const float* b2  = (const float*)d_in[10];
  const float* mw1 = (const float*)d_in[11];
  const float* mb1 = (const float*)d_in[12];
  const float* mw2 = (const float*)d_in[13];
  const float* mb2 = (const float*)d_in[14];
  const float* mw3 = (const float*)d_in[15];
  const float* mb3 = (const float*)d_in[16];

  const int N = in_sizes[0] / 128;
  const int E = in_sizes[1] / 2;
  const int P = in_sizes[2] / 2;
  const int EN = E + N;

  // ---- workspace carve-up (~55 MB) ----
  __bf16* z_bf  = (__bf16*)d_ws;                              // N*128 bf16
  __bf16* h_bf  = z_bf + (size_t)N * 128;                     // N*128 bf16
  unsigned char* xw8 = (unsigned char*)(h_bf + (size_t)N * 128);  // N*128 fp8
  unsigned char* uv8 = xw8 + (size_t)N * 128;                 // N*256 fp8
  __bf16* W1t   = (__bf16*)(uv8 + (size_t)N * 256);           // 128*128
  __bf16* W2t   = W1t + 16384;                                // 128*128
  __bf16* mw1t  = W2t + 16384;                                // 256*128
  __bf16* w2t   = mw1t + 32768;                               // 64*128
  float*  as_   = (float*)(w2t + 8192);                       // N*4 (layer1)
  float*  ad_   = as_ + (size_t)N * 4;                        // N*4
  int*    deg   = (int*)(ad_ + (size_t)N * 4);                // N (zero region)
  int*    cur   = deg + N;                                    // N (zeroed)
  float*  as2v  = (float*)(cur + N);                          // N (zeroed)
  float*  ad2v  = as2v + N;                                   // N (zeroed end)
  int* part     = (int*)(ad2v + N);                           // N
  int* bsum     = part + N;                                   // 256
  int* rowptr   = bsum + 256;                                 // N+1
  int* csr_src  = rowptr + (N + 1);                           // E+N
  float* out    = (float*)d_out;

  const int gEN = (EN + 255) / 256;
  const int nb  = (N + 255) / 256;           // 196 <= 256 (single-block scan2)
  const int gNG = (N + 31) / 32;

  // ---- CSR build (once; both layers share the graph) + zero accumulators --
  (void)hipMemsetAsync(deg, 0, (size_t)4 * N * sizeof(int), stream);  // deg,cur,as2v,ad2v
  hist_kernel <<<gEN, 256, 0, stream>>>(ei, deg, E, N);
  scan1_kernel<<<nb, 256, 0, stream>>>(deg, part, bsum, N);
  scan2_kernel<<<1, 256, 0, stream>>>(bsum, nb);
  scan3_kernel<<<nb, 256, 0, stream>>>(part, bsum, rowptr, N);
  fill_kernel <<<gEN, 256, 0, stream>>>(ei, rowptr, cur, csr_src, E, N);
  convw_kernel<<<128, 256, 0, stream>>>(W1, W2, mw1, mw2, W1t, W2t, mw1t, w2t);

  // ---- layer 1 (heads=4): x -> xw8 (+as_/ad_ fused) -> h_bf ----
  nodegemm_kernel<128, 4, true, false><<<gNG, 256, 0, stream>>>(
      nullptr, x, W1t, xw8, as1, ad1, as_, ad_, nullptr, N);
  gat_gather_kernel<4, true><<<(N + 3) / 4, 256, 0, stream>>>(
      csr_src, rowptr, xw8, as_, ad_, b1, h_bf, N);

  // ---- layer 2 (heads=1): h_bf -> xw8 (+as2v/ad2v fused) -> z_bf ----
  nodegemm_kernel<128, 1, false, false><<<gNG, 256, 0, stream>>>(
      h_bf, nullptr, W2t, xw8, as2, ad2, as2v, ad2v, nullptr, N);
  gat_gather_kernel<1, false><<<(N + 3) / 4, 256, 0, stream>>>(
      csr_src, rowptr, xw8, as2v, ad2v, b2, z_bf, N);

  // ---- uv = fp8(z @ [mw1_u | mw1_v] + mb1-fold on v-half) ----
  nodegemm_kernel<256, 0, false, true><<<gNG, 256, 0, stream>>>(
      z_bf, nullptr, mw1t, uv8, nullptr, nullptr, nullptr, nullptr, mb1, N);

  // ---- pair MLP (2-tile, fp8 gather, bf16 MFMA) ----
  pair_kernel<<<(P + 127) / 128, 256, 0, stream>>>(
      uv8, ep, w2t, mb2, mw3, mb3, out, P);
}